// Round 11
// baseline (275.867 us; speedup 1.0000x reference)
//
#include <hip/hip_runtime.h>
#include <math.h>

#define DIN    256
#define DEMB   128
#define NCB    4
#define MCODES 512
#define NCODE  2048
#define MARGIN 1.5e-4f      // >10x rigorous split-bf16 error bound (~1.3e-5)

using bf16x8 = __attribute__((ext_vector_type(8))) short;
using f32x16 = __attribute__((ext_vector_type(16))) float;

static __device__ __forceinline__ unsigned short f2bf(float f) {   // RNE f32->bf16
    unsigned u = __float_as_uint(f);
    u += 0x7FFFu + ((u >> 16) & 1u);
    return (unsigned short)(u >> 16);
}
static __device__ __forceinline__ float bf2f(unsigned short h) {
    return __uint_as_float(((unsigned)h) << 16);
}
static __device__ __forceinline__ float4 ld4(const float* p) {
    return *reinterpret_cast<const float4*>(p);
}

// ---------------------------------------------------------------------------
// Kernel 1: normalize codebook rows; emit (a) f32 copy for exact recheck,
// (b) hi/lo bf16 split in mfma_32x32x16 A-fragment order (tile ct = 16 KB
// contiguous: [kt 0..8][hl 0..2][lane 0..64][8 shorts]).
// ---------------------------------------------------------------------------
__global__ __launch_bounds__(256) void prep_codebook(
        const float* __restrict__ cb, float* __restrict__ cbn,
        unsigned short* __restrict__ cbA) {
    const int w = threadIdx.x >> 6, lane = threadIdx.x & 63;
    const int code = blockIdx.x * 4 + w;                 // 0..2047
    const float2 v = reinterpret_cast<const float2*>(cb + (size_t)code * DEMB)[lane];
    float ss = v.x * v.x + v.y * v.y;
#pragma unroll
    for (int m = 1; m < 64; m <<= 1) ss += __shfl_xor(ss, m, 64);
    const float rn = 1.0f / sqrtf(ss);
    const float x0 = v.x * rn, x1 = v.y * rn;
    reinterpret_cast<float2*>(cbn + (size_t)code * DEMB)[lane] = make_float2(x0, x1);

    const unsigned short h0 = f2bf(x0), h1 = f2bf(x1);
    const unsigned short l0 = f2bf(x0 - bf2f(h0)), l1 = f2bf(x1 - bf2f(h1));
    const int ct = code >> 5, ci = code & 31;
    const int kt = lane >> 3, g = (lane >> 2) & 1, i = 2 * (lane & 3);
    const size_t base = ((size_t)ct * 1024 + kt * 128 + g * 32 + ci) * 8 + i;
    *reinterpret_cast<ushort2*>(cbA + base)       = make_ushort2(h0, h1);  // hi
    *reinterpret_cast<ushort2*>(cbA + base + 512) = make_ushort2(l0, l1);  // lo
}

// ---------------------------------------------------------------------------
// Kernel 1b: 3-way split (hi/mid/lo bf16) of projector^T in A-fragment order.
// ---------------------------------------------------------------------------
__global__ __launch_bounds__(256) void prep_proj(
        const float* __restrict__ proj, unsigned short* __restrict__ pjA) {
    const int t = blockIdx.x * 256 + threadIdx.x;      // 4096 threads
    const int ci = t & 31, g = (t >> 5) & 1, kt = (t >> 6) & 15, mt = t >> 10;
    const int m = mt * 32 + ci;
    const size_t base = ((size_t)(mt * 16 + kt) * 3) * 512 + (size_t)(g * 32 + ci) * 8;
#pragma unroll
    for (int i = 0; i < 8; ++i) {
        const float v = proj[(size_t)(kt * 16 + g * 8 + i) * DEMB + m];
        const unsigned short h = f2bf(v);
        const float r1 = v - bf2f(h);                  // exact (Sterbenz)
        const unsigned short md = f2bf(r1);
        const float r2 = r1 - bf2f(md);                // exact
        pjA[base + i]        = h;
        pjA[base + 512 + i]  = md;
        pjA[base + 1024 + i] = f2bf(r2);
    }
}

// ---------------------------------------------------------------------------
// Kernel 2 (v4): projection via 6-pass split-bf16 MFMA. One mt per wave,
// no LDS/barriers, free-running. NEW: A-fragments prefetched into the
// 2-step register ping-pong alongside the input (r10 issued them inside
// the step -> ~300cy exposed L2 latency per kt; now the reload happens
// right after the MFMA cluster consumes the slot, one full step ahead).
// ---------------------------------------------------------------------------
__global__ __launch_bounds__(256) void project_mfma(
        const float* __restrict__ inp, const unsigned short* __restrict__ pjA,
        float* __restrict__ xw) {
    const int tid = threadIdx.x;
    const int lane = tid & 63, mt = tid >> 6, kg = lane >> 5;
    const int row = blockIdx.x * 32 + (lane & 31);
    const float* xr = inp + (size_t)row * DIN;
    const unsigned short* pL = pjA + (size_t)lane * 8;

    auto ldin = [&](float4& a, float4& b, int kt) {
        a = ld4(xr + kt * 16 + kg * 8);
        b = ld4(xr + kt * 16 + kg * 8 + 4);
    };
    auto ldA = [&](bf16x8& h, bf16x8& m, bf16x8& l, int kt) {
        const unsigned short* pf = pL + ((size_t)(mt * 16 + kt) * 3) * 512;
        h = *reinterpret_cast<const bf16x8*>(pf);
        m = *reinterpret_cast<const bf16x8*>(pf + 512);
        l = *reinterpret_cast<const bf16x8*>(pf + 1024);
    };

    f32x16 P, Q;
#pragma unroll
    for (int r = 0; r < 16; ++r) { P[r] = 0.0f; Q[r] = 0.0f; }

    auto do_step = [&](const float4& c0, const float4& c1,
                       const bf16x8& Ah, const bf16x8& Am, const bf16x8& Al) {
        const float xs[8] = {c0.x, c0.y, c0.z, c0.w, c1.x, c1.y, c1.z, c1.w};
        bf16x8 Bh, Bm, Bl;
#pragma unroll
        for (int e = 0; e < 8; ++e) {
            const float v = xs[e];
            const unsigned short h = f2bf(v);
            const float r1 = v - bf2f(h);
            const unsigned short md = f2bf(r1);
            const float r2 = r1 - bf2f(md);
            Bh[e] = (short)h; Bm[e] = (short)md; Bl[e] = (short)f2bf(r2);
        }
        P = __builtin_amdgcn_mfma_f32_32x32x16_bf16(Ah, Bh, P, 0, 0, 0);
        Q = __builtin_amdgcn_mfma_f32_32x32x16_bf16(Ah, Bm, Q, 0, 0, 0);
        Q = __builtin_amdgcn_mfma_f32_32x32x16_bf16(Am, Bh, Q, 0, 0, 0);
        Q = __builtin_amdgcn_mfma_f32_32x32x16_bf16(Ah, Bl, Q, 0, 0, 0);
        Q = __builtin_amdgcn_mfma_f32_32x32x16_bf16(Al, Bh, Q, 0, 0, 0);
        Q = __builtin_amdgcn_mfma_f32_32x32x16_bf16(Am, Bm, Q, 0, 0, 0);
    };

    float4 iA0, iA1, iB0, iB1;
    bf16x8 hA, mA, lA, hB, mB, lB;
    ldin(iA0, iA1, 0); ldA(hA, mA, lA, 0);
    ldin(iB0, iB1, 1); ldA(hB, mB, lB, 1);

#pragma unroll 1
    for (int kt = 0; kt < 16; kt += 2) {
        do_step(iA0, iA1, hA, mA, lA);                         // step kt
        if (kt + 2 < 16) { ldin(iA0, iA1, kt + 2); ldA(hA, mA, lA, kt + 2); }
        do_step(iB0, iB1, hB, mB, lB);                         // step kt+1
        if (kt + 3 < 16) { ldin(iB0, iB1, kt + 3); ldA(hB, mB, lB, kt + 3); }
    }

#pragma unroll
    for (int q = 0; q < 4; ++q) {
        float4 v;
        v.x = P[q * 4 + 0] + Q[q * 4 + 0];
        v.y = P[q * 4 + 1] + Q[q * 4 + 1];
        v.z = P[q * 4 + 2] + Q[q * 4 + 2];
        v.w = P[q * 4 + 3] + Q[q * 4 + 3];
        *reinterpret_cast<float4*>(xw + (size_t)row * DEMB + mt * 32 + q * 8 + kg * 4) = v;
    }
}

// ---------------------------------------------------------------------------
// Kernel 2 (fallback): f32 VALU projection (exact).
// ---------------------------------------------------------------------------
__global__ __launch_bounds__(256) void project_kernel(
        const float* __restrict__ inp, const float* __restrict__ proj,
        float* __restrict__ xw) {
    const int tid = threadIdx.x, tx = tid & 31, ty = tid >> 5;
    const int rowBase = blockIdx.x * 64;

    float acc1[8][4];
#pragma unroll
    for (int i = 0; i < 8; ++i)
#pragma unroll
        for (int j = 0; j < 4; ++j) acc1[i][j] = 0.0f;

    const float* inRow0 = inp + (size_t)(rowBase + ty) * DIN;
    const float* pjCol  = proj + tx * 4;

    float4 ivA[8], ivB[8], pjA[4], pjB[4];
    auto load_step = [&](float4 iv[8], float4 pj[4], int kk) {
#pragma unroll
        for (int j = 0; j < 4; ++j) pj[j] = ld4(pjCol + (size_t)(kk + j) * DEMB);
#pragma unroll
        for (int i = 0; i < 8; ++i) iv[i] = ld4(inRow0 + (size_t)(8 * i) * DIN + kk);
    };
    auto fma_step = [&](const float4 iv[8], const float4 pj[4]) {
#pragma unroll
        for (int i = 0; i < 8; ++i) {
            const float* ivp = reinterpret_cast<const float*>(&iv[i]);
#pragma unroll
            for (int j = 0; j < 4; ++j) {
                acc1[i][0] = fmaf(ivp[j], pj[j].x, acc1[i][0]);
                acc1[i][1] = fmaf(ivp[j], pj[j].y, acc1[i][1]);
                acc1[i][2] = fmaf(ivp[j], pj[j].z, acc1[i][2]);
                acc1[i][3] = fmaf(ivp[j], pj[j].w, acc1[i][3]);
            }
        }
    };
    load_step(ivA, pjA, 0);
#pragma unroll 1
    for (int k = 0; k < DIN; k += 8) {
        load_step(ivB, pjB, k + 4);
        fma_step(ivA, pjA);
        if (k + 8 < DIN) load_step(ivA, pjA, k + 8);
        fma_step(ivB, pjB);
    }
#pragma unroll
    for (int i = 0; i < 8; ++i) {
        const int r = rowBase + ty + 8 * i;
        *reinterpret_cast<float4*>(xw + (size_t)r * DEMB + tx * 4) =
            make_float4(acc1[i][0], acc1[i][1], acc1[i][2], acc1[i][3]);
    }
}

// ---------------------------------------------------------------------------
// Kernel 3 (v6): similarity + margin argmax, NO LDS / NO BARRIERS.
// Block = (128 rows, ONE cb), grid 2048, 4 independent free-running waves.
// r10 post-mortem: MFMA blocks its issuing wave, and the per-tile barrier
// locksteps all waves into the same phase -> MFMA/VALU pipes SUM instead of
// overlapping (34%+38% = the 127us wall). cbA is 1 MB = L2-resident; read
// A-fragments straight into a 2-deep register ping-pong. r5 tried this but
// __launch_bounds__(256,3) forced 84 VGPR under a ~130 live set -> scratch
// storm. Live set now ~100 VGPR (B 32 + single chained acc 16 + slots 16):
// no cap, no spill, 4-5 waves/SIMD of genuine phase diversity.
// ---------------------------------------------------------------------------
__global__ __launch_bounds__(256) void sim_kernel(
        const float* __restrict__ xw,
        const unsigned short* __restrict__ cbA,
        int* __restrict__ out, int* __restrict__ unc_cnt,
        int* __restrict__ unc_list) {
    const int tid = threadIdx.x;
    const int lane = tid & 63, wv = tid >> 6;     // wv 0..3
    const int kg = lane >> 5;
    const int cbi = blockIdx.x & 3;
    const int rowBase = (blockIdx.x >> 2) * 128;
    const int row = rowBase + wv * 32 + (lane & 31);

    // B-frag hoist with INLINE norm: load raw x, ss-reduce, split hi/lo.
    bf16x8 Bhi[8], Blo[8];
    {
        const float* xr = xw + (size_t)row * DEMB;
        float4 f0[8], f1[8];
        float ss = 0.0f;
#pragma unroll
        for (int kt = 0; kt < 8; ++kt) {
            f0[kt] = ld4(xr + kt * 16 + kg * 8);
            f1[kt] = ld4(xr + kt * 16 + kg * 8 + 4);
            ss += f0[kt].x * f0[kt].x + f0[kt].y * f0[kt].y +
                  f0[kt].z * f0[kt].z + f0[kt].w * f0[kt].w +
                  f1[kt].x * f1[kt].x + f1[kt].y * f1[kt].y +
                  f1[kt].z * f1[kt].z + f1[kt].w * f1[kt].w;
        }
        ss += __shfl_xor(ss, 32, 64);      // partner kg-half, same row
        const float rn = 1.0f / sqrtf(ss);
#pragma unroll
        for (int kt = 0; kt < 8; ++kt) {
            const float xs[8] = {f0[kt].x, f0[kt].y, f0[kt].z, f0[kt].w,
                                 f1[kt].x, f1[kt].y, f1[kt].z, f1[kt].w};
            bf16x8 hv, lv;
#pragma unroll
            for (int e = 0; e < 8; ++e) {
                const float xn = xs[e] * rn;
                const unsigned short h = f2bf(xn);
                hv[e] = (short)h;
                lv[e] = (short)f2bf(xn - bf2f(h));
            }
            Bhi[kt] = hv; Blo[kt] = lv;
        }
    }

    // A-stream: 128 k-steps (16 tiles x 8 kt); step s at byte offset s*2048
    // from this codebook's base; hi at +0, lo at +1024 B (512 shorts).
    const short* gA = (const short*)cbA + (size_t)cbi * 16 * 8192 + lane * 8;
    bf16x8 Ah0, Al0, Ah1, Al1;             // 2-step register ping-pong
    auto lda = [&](bf16x8& h, bf16x8& l, int s) {
        const short* p = gA + (size_t)s * 1024;
        h = *reinterpret_cast<const bf16x8*>(p);
        l = *reinterpret_cast<const bf16x8*>(p + 512);
    };
    lda(Ah0, Al0, 0);
    lda(Ah1, Al1, 1);

    f32x16 TWO;
#pragma unroll
    for (int r = 0; r < 16; ++r) TWO[r] = 2.0f;

    float t1 = -INFINITY, t2 = -INFINITY; int i1 = 0;

#pragma unroll 1
    for (int g = 0; g < 16; ++g) {
        f32x16 acc;
        const int s0 = g * 8;
#pragma unroll
        for (int kt = 0; kt < 8; ++kt) {   // single chained acc; slot freed
            const int nx = (s0 + kt + 2 < 128) ? s0 + kt + 2 : 127;
            if ((kt & 1) == 0) {
                acc = __builtin_amdgcn_mfma_f32_32x32x16_bf16(Ah0, Bhi[kt], kt ? acc : TWO, 0, 0, 0);
                acc = __builtin_amdgcn_mfma_f32_32x32x16_bf16(Ah0, Blo[kt], acc, 0, 0, 0);
                acc = __builtin_amdgcn_mfma_f32_32x32x16_bf16(Al0, Bhi[kt], acc, 0, 0, 0);
                lda(Ah0, Al0, nx);          // reload slot0 for step s+2
            } else {
                acc = __builtin_amdgcn_mfma_f32_32x32x16_bf16(Ah1, Bhi[kt], acc, 0, 0, 0);
                acc = __builtin_amdgcn_mfma_f32_32x32x16_bf16(Ah1, Blo[kt], acc, 0, 0, 0);
                acc = __builtin_amdgcn_mfma_f32_32x32x16_bf16(Al1, Bhi[kt], acc, 0, 0, 0);
                lda(Ah1, Al1, nx);          // reload slot1 for step s+2
            }
        }
        // top-2 update (gidx ascending within lane => first-max kept)
        const int base = g * 32;
#pragma unroll
        for (int r = 0; r < 16; ++r) {
            const float v = acc[r];
            const int gidx = base + (r & 3) + 8 * (r >> 2) + 4 * kg;
            t2 = fmaxf(t2, fminf(v, t1));
            if (v > t1) { t1 = v; i1 = gidx; }
        }
    }

    // merge kg halves (lane L <-> L^32: same row, disjoint codes)
    const float o1 = __shfl_xor(t1, 32, 64);
    const float o2 = __shfl_xor(t2, 32, 64);
    const int   oi = __shfl_xor(i1, 32, 64);
    const float m2 = fmaxf(fmaxf(t2, o2), fminf(t1, o1));
    if (o1 > t1 || (o1 == t1 && oi < i1)) { t1 = o1; i1 = oi; }
    const bool unc = (t1 - m2) < MARGIN;
    if (lane < 32 && !unc)
        out[(size_t)row * NCB + cbi] = i1;

    unsigned long long msk = __ballot(unc && lane < 32);
    if (lane == 0 && msk) {
        const int n = __popcll(msk);
        int base = atomicAdd(unc_cnt, n);
        while (msk) {
            const int r = __ffsll(msk) - 1; msk &= msk - 1;
            unc_list[base++] = ((rowBase + wv * 32 + r) << 2) | cbi;
        }
    }
}

// ---------------------------------------------------------------------------
// Kernel 4: exact recheck. Recomputes x EXACTLY (f32 inp@proj) per item,
// then exact f32 dots vs 512 codes; first-max tie rules. Unrolled so loads
// pipeline (r8 lesson).
// ---------------------------------------------------------------------------
__global__ __launch_bounds__(256) void recheck_kernel(
        const float* __restrict__ inp, const float* __restrict__ proj,
        const float* __restrict__ cbn,
        const int* __restrict__ unc_cnt, const int* __restrict__ unc_list,
        int* __restrict__ out) {
    __shared__ float sx[4][DEMB];
    const int lane = threadIdx.x & 63, wv = threadIdx.x >> 6;
    const int n = *unc_cnt;
    for (int it = blockIdx.x * 4 + wv; it < n; it += gridDim.x * 4) {
        const int item = unc_list[it];
        const int row = item >> 2, cbi = item & 3;
        {
            const float* ir = inp + (size_t)row * DIN;
            float a0 = 0.0f, a1 = 0.0f;
#pragma unroll 2
            for (int k = 0; k < DIN; k += 4) {
                const float4 iv = ld4(ir + k);
                const float* ivp = reinterpret_cast<const float*>(&iv);
#pragma unroll
                for (int j = 0; j < 4; ++j) {
                    a0 = fmaf(ivp[j], proj[(size_t)(k + j) * DEMB + lane],      a0);
                    a1 = fmaf(ivp[j], proj[(size_t)(k + j) * DEMB + lane + 64], a1);
                }
            }
            sx[wv][lane] = a0; sx[wv][lane + 64] = a1;   // same-wave LDS exchange
        }
        float best = -INFINITY; int bi = 0;
#pragma unroll 2
        for (int j = 0; j < 8; ++j) {
            const int c = lane + 64 * j;
            const float* cv = cbn + ((size_t)cbi * MCODES + c) * DEMB;
            float s0 = 0, s1 = 0, s2 = 0, s3 = 0;
#pragma unroll 4
            for (int k = 0; k < DEMB; k += 4) {
                const float4 xk = ld4(&sx[wv][k]);
                const float4 ck = ld4(cv + k);
                s0 = fmaf(xk.x, ck.x, s0); s1 = fmaf(xk.y, ck.y, s1);
                s2 = fmaf(xk.z, ck.z, s2); s3 = fmaf(xk.w, ck.w, s3);
            }
            const float s = (s0 + s1) + (s2 + s3);
            if (s > best) { best = s; bi = c; }
        }
#pragma unroll
        for (int mm = 1; mm < 64; mm <<= 1) {
            const float ov = __shfl_xor(best, mm, 64);
            const int   oc = __shfl_xor(bi, mm, 64);
            if (ov > best || (ov == best && oc < bi)) { best = ov; bi = oc; }
        }
        if (lane == 0) out[(size_t)row * NCB + cbi] = bi;
    }
}

// ---------------------------------------------------------------------------
// Fallback (ws too small): round-3 fused kernel (proven, 2 MB ws).
// ---------------------------------------------------------------------------
__global__ __launch_bounds__(256) void fused_quantize_kernel(
        const float* __restrict__ inp, const float* __restrict__ proj,
        const float* __restrict__ cbn, const unsigned short* __restrict__ cbA,
        int* __restrict__ out) {
    __shared__ float sX[128][132];
    __shared__ float sRn[128];
    const int tid = threadIdx.x;
    const int tx = tid & 31, ty = tid >> 5;
    const int rowBase = blockIdx.x * 128;

#pragma unroll 1
    for (int p = 0; p < 2; ++p) {
        float acc1[8][4];
#pragma unroll
        for (int i = 0; i < 8; ++i)
#pragma unroll
            for (int j = 0; j < 4; ++j) acc1[i][j] = 0.0f;
        const float* inRow0 = inp + (size_t)(rowBase + p * 64 + ty) * DIN;
        const float* pjCol  = proj + tx * 4;
        float4 ivA[8], ivB[8], pjA[4], pjB[4];
        auto load_step = [&](float4 iv[8], float4 pj[4], int kk) {
#pragma unroll
            for (int j = 0; j < 4; ++j) pj[j] = ld4(pjCol + (size_t)(kk + j) * DEMB);
#pragma unroll
            for (int i = 0; i < 8; ++i) iv[i] = ld4(inRow0 + (size_t)(8 * i) * DIN + kk);
        };
        auto fma_step = [&](const float4 iv[8], const float4 pj[4]) {
#pragma unroll
            for (int i = 0; i < 8; ++i) {
                const float* ivp = reinterpret_cast<const float*>(&iv[i]);
#pragma unroll
                for (int j = 0; j < 4; ++j) {
                    acc1[i][0] = fmaf(ivp[j], pj[j].x, acc1[i][0]);
                    acc1[i][1] = fmaf(ivp[j], pj[j].y, acc1[i][1]);
                    acc1[i][2] = fmaf(ivp[j], pj[j].z, acc1[i][2]);
                    acc1[i][3] = fmaf(ivp[j], pj[j].w, acc1[i][3]);
                }
            }
        };
        load_step(ivA, pjA, 0);
#pragma unroll 1
        for (int k = 0; k < DIN; k += 8) {
            load_step(ivB, pjB, k + 4);
            fma_step(ivA, pjA);
            if (k + 8 < DIN) load_step(ivA, pjA, k + 8);
            fma_step(ivB, pjB);
        }
#pragma unroll
        for (int i = 0; i < 8; ++i) {
            const int r = p * 64 + ty + 8 * i;
            float ss = acc1[i][0] * acc1[i][0] + acc1[i][1] * acc1[i][1] +
                       acc1[i][2] * acc1[i][2] + acc1[i][3] * acc1[i][3];
#pragma unroll
            for (int mm = 1; mm < 32; mm <<= 1) ss += __shfl_xor(ss, mm, 64);
            if (tx == 0) sRn[r] = 1.0f / sqrtf(ss);
            *reinterpret_cast<float4*>(&sX[r][tx * 4]) =
                make_float4(acc1[i][0], acc1[i][1], acc1[i][2], acc1[i][3]);
        }
    }
    __syncthreads();

    const int lane = tid & 63, wv = tid >> 6;
    const int kg = lane >> 5;
    const int rowL = wv * 32 + (lane & 31);
    bf16x8 Bhi[8], Blo[8];
    {
        const float rn = sRn[rowL];
#pragma unroll
        for (int kt = 0; kt < 8; ++kt) {
            const int k0 = kt * 16 + kg * 8;
            float4 f0 = ld4(&sX[rowL][k0]);
            float4 f1 = ld4(&sX[rowL][k0 + 4]);
            float xs[8] = {f0.x, f0.y, f0.z, f0.w, f1.x, f1.y, f1.z, f1.w};
            bf16x8 hv, lv;
#pragma unroll
            for (int e = 0; e < 8; ++e) {
                const float xn = xs[e] * rn;
                const unsigned short h = f2bf(xn);
                hv[e] = (short)h;
                lv[e] = (short)f2bf(xn - bf2f(h));
            }
            Bhi[kt] = hv; Blo[kt] = lv;
        }
    }
    float t1 = -INFINITY, t2 = -INFINITY; int i1 = 0;
    const short* pA = reinterpret_cast<const short*>(cbA) + (size_t)lane * 8;
#pragma unroll 1
    for (int ct = 0; ct < 64; ++ct) {
        if ((ct & 1) == 0) __syncthreads();
        const short* pct = pA + (size_t)ct * 8192;
        f32x16 accA, accB;
#pragma unroll
        for (int r = 0; r < 16; ++r) { accA[r] = 0.0f; accB[r] = 0.0f; }
#pragma unroll
        for (int kt = 0; kt < 8; ++kt) {
            const bf16x8 Ahi = *reinterpret_cast<const bf16x8*>(pct + kt * 1024);
            const bf16x8 Alo = *reinterpret_cast<const bf16x8*>(pct + kt * 1024 + 512);
            accA = __builtin_amdgcn_mfma_f32_32x32x16_bf16(Ahi, Bhi[kt], accA, 0, 0, 0);
            accB = __builtin_amdgcn_mfma_f32_32x32x16_bf16(Ahi, Blo[kt], accB, 0, 0, 0);
            accB = __builtin_amdgcn_mfma_f32_32x32x16_bf16(Alo, Bhi[kt], accB, 0, 0, 0);
        }
#pragma unroll
        for (int r = 0; r < 16; ++r) {
            const float v = accA[r] + accB[r];
            const int gidx = ct * 32 + ((r & 3) + 8 * (r >> 2) + 4 * kg);
            t2 = fmaxf(t2, fminf(v, t1));
            if (v > t1) { t1 = v; i1 = gidx; }
        }
        if ((ct & 15) == 15) {
            const int cbi = ct >> 4;
            const float o1 = __shfl_xor(t1, 32, 64);
            const float o2 = __shfl_xor(t2, 32, 64);
            const int   oi = __shfl_xor(i1, 32, 64);
            const float m2 = fmaxf(fmaxf(t2, o2), fminf(t1, o1));
            if (o1 > t1 || (o1 == t1 && oi < i1)) { t1 = o1; i1 = oi; }
            const bool unc = (t1 - m2) < MARGIN;
            if (lane < 32 && !unc)
                out[(size_t)(rowBase + rowL) * NCB + cbi] = i1 - cbi * MCODES;
            unsigned long long msk = __ballot(unc && lane < 32);
            while (msk) {
                const int r = __ffsll(msk) - 1; msk &= msk - 1;
                const int rl = wv * 32 + r;
                float best = -INFINITY; int bi = 0;
#pragma unroll 1
                for (int j = 0; j < 8; ++j) {
                    const int c = lane + 64 * j;
                    const float* cv = cbn + ((size_t)cbi * MCODES + c) * DEMB;
                    float s0 = 0, s1 = 0, s2 = 0, s3 = 0;
#pragma unroll
                    for (int k = 0; k < DEMB; k += 4) {
                        const float4 xk = ld4(&sX[rl][k]);
                        const float4 ck = ld4(cv + k);
                        s0 = fmaf(xk.x, ck.x, s0); s1 = fmaf(xk.y, ck.y, s1);
                        s2 = fmaf(xk.z, ck.z, s2); s3 = fmaf(xk.w, ck.w, s3);
                    }
                    const float s = (s0 + s1) + (s2 + s3);
                    if (s > best) { best = s; bi = c; }
                }
#pragma unroll
                for (int mm = 1; mm < 64; mm <<= 1) {
                    const float ov = __shfl_xor(best, mm, 64);
                    const int   oc = __shfl_xor(bi, mm, 64);
                    if (ov > best || (ov == best && oc < bi)) { best = ov; bi = oc; }
                }
                if (lane == 0) out[(size_t)(rowBase + rl) * NCB + cbi] = bi;
            }
            t1 = -INFINITY; t2 = -INFINITY; i1 = 0;
        }
    }
}

// ---------------------------------------------------------------------------
extern "C" void kernel_launch(void* const* d_in, const int* in_sizes, int n_in,
                              void* d_out, int out_size, void* d_ws, size_t ws_size,
                              hipStream_t stream) {
    const float* inp  = (const float*)d_in[0];   // [8,16,512,256]
    const float* proj = (const float*)d_in[1];   // [256,128]
    const float* cb   = (const float*)d_in[2];   // [4,512,128]
    int* out = (int*)d_out;                      // [8,16,512,4] int32

    char* ws = (char*)d_ws;
    float* cbn = (float*)ws;                                     // 1 MB
    unsigned short* cbA = (unsigned short*)(ws + (1 << 20));     // 1 MB
    float* xw  = (float*)(ws + (2 << 20) + (1 << 18));           // 32 MB
    const size_t off_cnt = (size_t)(2 << 20) + (1 << 18) + ((size_t)32 << 20);
    int* unc_cnt  = (int*)(ws + off_cnt);                        // 4 B (pad 256)
    int* unc_list = (int*)(ws + off_cnt + 256);                  // 1 MB
    const size_t off_pjA = off_cnt + 256 + (1 << 20);
    unsigned short* pjA = (unsigned short*)(ws + off_pjA);       // 192 KB
    const size_t need_old = off_pjA;
    const size_t need_new = off_pjA + 192 * 1024;

    hipLaunchKernelGGL(prep_codebook, dim3(NCODE / 4), dim3(256), 0, stream,
                       cb, cbn, cbA);
    if (ws_size >= need_old) {
        hipMemsetAsync(unc_cnt, 0, 4, stream);
        if (ws_size >= need_new) {
            hipLaunchKernelGGL(prep_proj, dim3(16), dim3(256), 0, stream, proj, pjA);
            hipLaunchKernelGGL(project_mfma, dim3(2048), dim3(256), 0, stream,
                               inp, pjA, xw);
        } else {
            hipLaunchKernelGGL(project_kernel, dim3(1024), dim3(256), 0, stream,
                               inp, proj, xw);
        }
        hipLaunchKernelGGL(sim_kernel, dim3(2048), dim3(256), 0, stream,
                           xw, cbA, out, unc_cnt, unc_list);
        hipLaunchKernelGGL(recheck_kernel, dim3(1024), dim3(256), 0, stream,
                           inp, proj, cbn, unc_cnt, unc_list, out);
    } else {
        hipLaunchKernelGGL(fused_quantize_kernel, dim3(512), dim3(256), 0, stream,
                           inp, proj, cbn, cbA, out);
    }
}

// Round 12
// 219.627 us; speedup vs baseline: 1.2561x; 1.2561x over previous
//
#include <hip/hip_runtime.h>
#include <math.h>

#define DIN    256
#define DEMB   128
#define NCB    4
#define MCODES 512
#define NCODE  2048
#define MARGIN 1.5e-4f      // >10x rigorous split-bf16 error bound (~1.3e-5)

using bf16x8 = __attribute__((ext_vector_type(8))) short;
using f32x16 = __attribute__((ext_vector_type(16))) float;

static __device__ __forceinline__ unsigned short f2bf(float f) {   // RNE f32->bf16
    unsigned u = __float_as_uint(f);
    u += 0x7FFFu + ((u >> 16) & 1u);
    return (unsigned short)(u >> 16);
}
static __device__ __forceinline__ float bf2f(unsigned short h) {
    return __uint_as_float(((unsigned)h) << 16);
}
static __device__ __forceinline__ float4 ld4(const float* p) {
    return *reinterpret_cast<const float4*>(p);
}
// async global->LDS DMA, 16B per lane, wave-uniform LDS base (guide §5)
static __device__ __forceinline__ void gload_lds16(const void* g, void* l) {
    __builtin_amdgcn_global_load_lds(
        (const __attribute__((address_space(1))) void*)g,
        (__attribute__((address_space(3))) void*)l, 16, 0, 0);
}

// ---------------------------------------------------------------------------
// Kernel 1: normalize codebook rows; emit (a) f32 copy for exact recheck,
// (b) hi/lo bf16 split in mfma_32x32x16 A-fragment order (tile ct = 16 KB
// contiguous: [kt 0..8][hl 0..2][lane 0..64][8 shorts]).
// ---------------------------------------------------------------------------
__global__ __launch_bounds__(256) void prep_codebook(
        const float* __restrict__ cb, float* __restrict__ cbn,
        unsigned short* __restrict__ cbA) {
    const int w = threadIdx.x >> 6, lane = threadIdx.x & 63;
    const int code = blockIdx.x * 4 + w;                 // 0..2047
    const float2 v = reinterpret_cast<const float2*>(cb + (size_t)code * DEMB)[lane];
    float ss = v.x * v.x + v.y * v.y;
#pragma unroll
    for (int m = 1; m < 64; m <<= 1) ss += __shfl_xor(ss, m, 64);
    const float rn = 1.0f / sqrtf(ss);
    const float x0 = v.x * rn, x1 = v.y * rn;
    reinterpret_cast<float2*>(cbn + (size_t)code * DEMB)[lane] = make_float2(x0, x1);

    const unsigned short h0 = f2bf(x0), h1 = f2bf(x1);
    const unsigned short l0 = f2bf(x0 - bf2f(h0)), l1 = f2bf(x1 - bf2f(h1));
    const int ct = code >> 5, ci = code & 31;
    const int kt = lane >> 3, g = (lane >> 2) & 1, i = 2 * (lane & 3);
    const size_t base = ((size_t)ct * 1024 + kt * 128 + g * 32 + ci) * 8 + i;
    *reinterpret_cast<ushort2*>(cbA + base)       = make_ushort2(h0, h1);  // hi
    *reinterpret_cast<ushort2*>(cbA + base + 512) = make_ushort2(l0, l1);  // lo
}

// ---------------------------------------------------------------------------
// Kernel 1b: 3-way split (hi/mid/lo bf16) of projector^T in A-fragment order.
// ---------------------------------------------------------------------------
__global__ __launch_bounds__(256) void prep_proj(
        const float* __restrict__ proj, unsigned short* __restrict__ pjA) {
    const int t = blockIdx.x * 256 + threadIdx.x;      // 4096 threads
    const int ci = t & 31, g = (t >> 5) & 1, kt = (t >> 6) & 15, mt = t >> 10;
    const int m = mt * 32 + ci;
    const size_t base = ((size_t)(mt * 16 + kt) * 3) * 512 + (size_t)(g * 32 + ci) * 8;
#pragma unroll
    for (int i = 0; i < 8; ++i) {
        const float v = proj[(size_t)(kt * 16 + g * 8 + i) * DEMB + m];
        const unsigned short h = f2bf(v);
        const float r1 = v - bf2f(h);                  // exact (Sterbenz)
        const unsigned short md = f2bf(r1);
        const float r2 = r1 - bf2f(md);                // exact
        pjA[base + i]        = h;
        pjA[base + 512 + i]  = md;
        pjA[base + 1024 + i] = f2bf(r2);
    }
}

// ---------------------------------------------------------------------------
// Kernel 2 (v4): projection via 6-pass split-bf16 MFMA. One mt per wave,
// no LDS/barriers, free-running; A-fragments prefetched in the 2-step
// register ping-pong alongside the input.
// ---------------------------------------------------------------------------
__global__ __launch_bounds__(256) void project_mfma(
        const float* __restrict__ inp, const unsigned short* __restrict__ pjA,
        float* __restrict__ xw) {
    const int tid = threadIdx.x;
    const int lane = tid & 63, mt = tid >> 6, kg = lane >> 5;
    const int row = blockIdx.x * 32 + (lane & 31);
    const float* xr = inp + (size_t)row * DIN;
    const unsigned short* pL = pjA + (size_t)lane * 8;

    auto ldin = [&](float4& a, float4& b, int kt) {
        a = ld4(xr + kt * 16 + kg * 8);
        b = ld4(xr + kt * 16 + kg * 8 + 4);
    };
    auto ldA = [&](bf16x8& h, bf16x8& m, bf16x8& l, int kt) {
        const unsigned short* pf = pL + ((size_t)(mt * 16 + kt) * 3) * 512;
        h = *reinterpret_cast<const bf16x8*>(pf);
        m = *reinterpret_cast<const bf16x8*>(pf + 512);
        l = *reinterpret_cast<const bf16x8*>(pf + 1024);
    };

    f32x16 P, Q;
#pragma unroll
    for (int r = 0; r < 16; ++r) { P[r] = 0.0f; Q[r] = 0.0f; }

    auto do_step = [&](const float4& c0, const float4& c1,
                       const bf16x8& Ah, const bf16x8& Am, const bf16x8& Al) {
        const float xs[8] = {c0.x, c0.y, c0.z, c0.w, c1.x, c1.y, c1.z, c1.w};
        bf16x8 Bh, Bm, Bl;
#pragma unroll
        for (int e = 0; e < 8; ++e) {
            const float v = xs[e];
            const unsigned short h = f2bf(v);
            const float r1 = v - bf2f(h);
            const unsigned short md = f2bf(r1);
            const float r2 = r1 - bf2f(md);
            Bh[e] = (short)h; Bm[e] = (short)md; Bl[e] = (short)f2bf(r2);
        }
        P = __builtin_amdgcn_mfma_f32_32x32x16_bf16(Ah, Bh, P, 0, 0, 0);
        Q = __builtin_amdgcn_mfma_f32_32x32x16_bf16(Ah, Bm, Q, 0, 0, 0);
        Q = __builtin_amdgcn_mfma_f32_32x32x16_bf16(Am, Bh, Q, 0, 0, 0);
        Q = __builtin_amdgcn_mfma_f32_32x32x16_bf16(Ah, Bl, Q, 0, 0, 0);
        Q = __builtin_amdgcn_mfma_f32_32x32x16_bf16(Al, Bh, Q, 0, 0, 0);
        Q = __builtin_amdgcn_mfma_f32_32x32x16_bf16(Am, Bm, Q, 0, 0, 0);
    };

    float4 iA0, iA1, iB0, iB1;
    bf16x8 hA, mA, lA, hB, mB, lB;
    ldin(iA0, iA1, 0); ldA(hA, mA, lA, 0);
    ldin(iB0, iB1, 1); ldA(hB, mB, lB, 1);

#pragma unroll 1
    for (int kt = 0; kt < 16; kt += 2) {
        do_step(iA0, iA1, hA, mA, lA);                         // step kt
        if (kt + 2 < 16) { ldin(iA0, iA1, kt + 2); ldA(hA, mA, lA, kt + 2); }
        do_step(iB0, iB1, hB, mB, lB);                         // step kt+1
        if (kt + 3 < 16) { ldin(iB0, iB1, kt + 3); ldA(hB, mB, lB, kt + 3); }
    }

#pragma unroll
    for (int q = 0; q < 4; ++q) {
        float4 v;
        v.x = P[q * 4 + 0] + Q[q * 4 + 0];
        v.y = P[q * 4 + 1] + Q[q * 4 + 1];
        v.z = P[q * 4 + 2] + Q[q * 4 + 2];
        v.w = P[q * 4 + 3] + Q[q * 4 + 3];
        *reinterpret_cast<float4*>(xw + (size_t)row * DEMB + mt * 32 + q * 8 + kg * 4) = v;
    }
}

// ---------------------------------------------------------------------------
// Kernel 2 (fallback): f32 VALU projection (exact).
// ---------------------------------------------------------------------------
__global__ __launch_bounds__(256) void project_kernel(
        const float* __restrict__ inp, const float* __restrict__ proj,
        float* __restrict__ xw) {
    const int tid = threadIdx.x, tx = tid & 31, ty = tid >> 5;
    const int rowBase = blockIdx.x * 64;

    float acc1[8][4];
#pragma unroll
    for (int i = 0; i < 8; ++i)
#pragma unroll
        for (int j = 0; j < 4; ++j) acc1[i][j] = 0.0f;

    const float* inRow0 = inp + (size_t)(rowBase + ty) * DIN;
    const float* pjCol  = proj + tx * 4;

    float4 ivA[8], ivB[8], pjA[4], pjB[4];
    auto load_step = [&](float4 iv[8], float4 pj[4], int kk) {
#pragma unroll
        for (int j = 0; j < 4; ++j) pj[j] = ld4(pjCol + (size_t)(kk + j) * DEMB);
#pragma unroll
        for (int i = 0; i < 8; ++i) iv[i] = ld4(inRow0 + (size_t)(8 * i) * DIN + kk);
    };
    auto fma_step = [&](const float4 iv[8], const float4 pj[4]) {
#pragma unroll
        for (int i = 0; i < 8; ++i) {
            const float* ivp = reinterpret_cast<const float*>(&iv[i]);
#pragma unroll
            for (int j = 0; j < 4; ++j) {
                acc1[i][0] = fmaf(ivp[j], pj[j].x, acc1[i][0]);
                acc1[i][1] = fmaf(ivp[j], pj[j].y, acc1[i][1]);
                acc1[i][2] = fmaf(ivp[j], pj[j].z, acc1[i][2]);
                acc1[i][3] = fmaf(ivp[j], pj[j].w, acc1[i][3]);
            }
        }
    };
    load_step(ivA, pjA, 0);
#pragma unroll 1
    for (int k = 0; k < DIN; k += 8) {
        load_step(ivB, pjB, k + 4);
        fma_step(ivA, pjA);
        if (k + 8 < DIN) load_step(ivA, pjA, k + 8);
        fma_step(ivB, pjB);
    }
#pragma unroll
    for (int i = 0; i < 8; ++i) {
        const int r = rowBase + ty + 8 * i;
        *reinterpret_cast<float4*>(xw + (size_t)r * DEMB + tx * 4) =
            make_float4(acc1[i][0], acc1[i][1], acc1[i][2], acc1[i][3]);
    }
}

// ---------------------------------------------------------------------------
// Kernel 3 (v7): similarity + margin argmax. r10 skeleton (proven best:
// LDS 3-buffer DMA pipeline, counted vmcnt(4), 1 barrier/tile, grid 2048
// cb-split, deferred epilogue, setprio) + two deltas:
//  - THREE independent MFMA chains (r9/r10's single chained acc was a
//    24-deep dependent chain = latency-bound; 3 chains restore 8-deep).
//  - FULL unroll of the 16-tile loop: buffer indices & addresses become
//    compile-time, SSA renames kill the per-tile acc copies and address
//    math that sat in the serial path at ~2 waves/SIMD.
// r11 lesson kept: LDS staging is load-sharing (4 waves share one 16 KB
// tile fetch); global-read per-wave streams quadruple L2 traffic.
// ---------------------------------------------------------------------------
__global__ __launch_bounds__(256) void sim_kernel(
        const float* __restrict__ xw,
        const unsigned short* __restrict__ cbA,
        int* __restrict__ out, int* __restrict__ unc_cnt,
        int* __restrict__ unc_list) {
    __shared__ __align__(16) short sA[3][8192];   // 3 x 16 KB tile buffers
    const int tid = threadIdx.x;
    const int lane = tid & 63, wv = tid >> 6;     // wv 0..3
    const int kg = lane >> 5;
    const int cbi = blockIdx.x & 3;
    const int rowBase = (blockIdx.x >> 2) * 128;
    const int row = rowBase + wv * 32 + (lane & 31);

    const short* gA = (const short*)cbA + (size_t)cbi * 16 * 8192;
    auto stage = [&](int buf, int t) {   // 16 KB tile, 4 DMA instrs/thread
        const short* g = gA + (size_t)t * 8192 + wv * 2048 + lane * 8;
        short* l = &sA[buf][wv * 2048];
#pragma unroll
        for (int c = 0; c < 4; ++c)
            gload_lds16(g + c * 512, l + c * 512);
    };

    stage(0, 0);
    stage(1, 1);

    // B-frag hoist with INLINE norm: load raw x, ss-reduce, split hi/lo.
    bf16x8 Bhi[8], Blo[8];
    {
        const float* xr = xw + (size_t)row * DEMB;
        float4 f0[8], f1[8];
        float ss = 0.0f;
#pragma unroll
        for (int kt = 0; kt < 8; ++kt) {
            f0[kt] = ld4(xr + kt * 16 + kg * 8);
            f1[kt] = ld4(xr + kt * 16 + kg * 8 + 4);
            ss += f0[kt].x * f0[kt].x + f0[kt].y * f0[kt].y +
                  f0[kt].z * f0[kt].z + f0[kt].w * f0[kt].w +
                  f1[kt].x * f1[kt].x + f1[kt].y * f1[kt].y +
                  f1[kt].z * f1[kt].z + f1[kt].w * f1[kt].w;
        }
        ss += __shfl_xor(ss, 32, 64);      // partner kg-half, same row
        const float rn = 1.0f / sqrtf(ss);
#pragma unroll
        for (int kt = 0; kt < 8; ++kt) {
            const float xs[8] = {f0[kt].x, f0[kt].y, f0[kt].z, f0[kt].w,
                                 f1[kt].x, f1[kt].y, f1[kt].z, f1[kt].w};
            bf16x8 hv, lv;
#pragma unroll
            for (int e = 0; e < 8; ++e) {
                const float xn = xs[e] * rn;
                const unsigned short h = f2bf(xn);
                hv[e] = (short)h;
                lv[e] = (short)f2bf(xn - bf2f(h));
            }
            Bhi[kt] = hv; Blo[kt] = lv;
        }
    }

    f32x16 TWO, ZERO;
#pragma unroll
    for (int r = 0; r < 16; ++r) { TWO[r] = 2.0f; ZERO[r] = 0.0f; }

    float t1 = -INFINITY, t2 = -INFINITY; int i1 = 0;
    f32x16 cA = TWO, cB1 = ZERO, cB2 = ZERO;   // prev-tile chains (g=0 unused)

    auto epi = [&](const f32x16& vA, const f32x16& vB1, const f32x16& vB2,
                   int gprev) {
        const int base = gprev * 32;
#pragma unroll
        for (int r = 0; r < 16; ++r) {
            const float v = (vA[r] + vB1[r]) + vB2[r];
            const int gidx = base + (r & 3) + 8 * (r >> 2) + 4 * kg;
            t2 = fmaxf(t2, fminf(v, t1));
            if (v > t1) { t1 = v; i1 = gidx; }
        }
    };

#pragma unroll
    for (int g = 0; g < 16; ++g) {         // FULL unroll: all indices static
        if (g < 15) asm volatile("s_waitcnt vmcnt(4)" ::: "memory");
        else        asm volatile("s_waitcnt vmcnt(0)" ::: "memory");
        __builtin_amdgcn_s_barrier();
        asm volatile("" ::: "memory");
        if (g + 2 < 16) stage((g + 2) % 3, g + 2);

        const short* pa = &sA[g % 3][lane * 8];
        f32x16 nA, nB1, nB2;
        __builtin_amdgcn_s_setprio(1);
#pragma unroll
        for (int kt = 0; kt < 8; ++kt) {   // 3 independent 8-deep chains
            const bf16x8 Ahi = *reinterpret_cast<const bf16x8*>(pa + kt * 1024);
            const bf16x8 Alo = *reinterpret_cast<const bf16x8*>(pa + kt * 1024 + 512);
            nA  = __builtin_amdgcn_mfma_f32_32x32x16_bf16(Ahi, Bhi[kt], kt ? nA  : TWO,  0, 0, 0);
            nB1 = __builtin_amdgcn_mfma_f32_32x32x16_bf16(Ahi, Blo[kt], kt ? nB1 : ZERO, 0, 0, 0);
            nB2 = __builtin_amdgcn_mfma_f32_32x32x16_bf16(Alo, Bhi[kt], kt ? nB2 : ZERO, 0, 0, 0);
        }
        __builtin_amdgcn_s_setprio(0);

        if (g > 0) epi(cA, cB1, cB2, g - 1);   // prev tile hides in MFMA shadow
        cA = nA; cB1 = nB1; cB2 = nB2;         // SSA rename after unroll
    }
    epi(cA, cB1, cB2, 15);

    // merge kg halves (lane L <-> L^32: same row, disjoint codes)
    const float o1 = __shfl_xor(t1, 32, 64);
    const float o2 = __shfl_xor(t2, 32, 64);
    const int   oi = __shfl_xor(i1, 32, 64);
    const float m2 = fmaxf(fmaxf(t2, o2), fminf(t1, o1));
    if (o1 > t1 || (o1 == t1 && oi < i1)) { t1 = o1; i1 = oi; }
    const bool unc = (t1 - m2) < MARGIN;
    if (lane < 32 && !unc)
        out[(size_t)row * NCB + cbi] = i1;

    unsigned long long msk = __ballot(unc && lane < 32);
    if (lane == 0 && msk) {
        const int n = __popcll(msk);
        int base = atomicAdd(unc_cnt, n);
        while (msk) {
            const int r = __ffsll(msk) - 1; msk &= msk - 1;
            unc_list[base++] = ((rowBase + wv * 32 + r) << 2) | cbi;
        }
    }
}

// ---------------------------------------------------------------------------
// Kernel 4 (v2): exact recheck, ONE BLOCK PER ITEM (grid-stride). Wave 0
// recomputes x exactly (f32 inp@proj); after barrier the 4 waves scan 128
// codes each (wave w: codes w*128 + lane + 64j, ascending); per-wave
// first-max reduce, then LDS merge preferring lower global index (wave
// ranges are disjoint ascending, so value-then-lower-wave = first-max).
// ---------------------------------------------------------------------------
__global__ __launch_bounds__(256) void recheck_kernel(
        const float* __restrict__ inp, const float* __restrict__ proj,
        const float* __restrict__ cbn,
        const int* __restrict__ unc_cnt, const int* __restrict__ unc_list,
        int* __restrict__ out) {
    __shared__ float sx[DEMB];
    __shared__ float sBest[4];
    __shared__ int   sIdx[4];
    const int lane = threadIdx.x & 63, wv = threadIdx.x >> 6;
    const int n = *unc_cnt;
    for (int it = blockIdx.x; it < n; it += gridDim.x) {
        const int item = unc_list[it];
        const int row = item >> 2, cbi = item & 3;
        if (wv == 0) {                     // exact x: lane owns cols lane,lane+64
            const float* ir = inp + (size_t)row * DIN;
            float a0 = 0.0f, a1 = 0.0f;
#pragma unroll 2
            for (int k = 0; k < DIN; k += 4) {
                const float4 iv = ld4(ir + k);
                const float* ivp = reinterpret_cast<const float*>(&iv);
#pragma unroll
                for (int j = 0; j < 4; ++j) {
                    a0 = fmaf(ivp[j], proj[(size_t)(k + j) * DEMB + lane],      a0);
                    a1 = fmaf(ivp[j], proj[(size_t)(k + j) * DEMB + lane + 64], a1);
                }
            }
            sx[lane] = a0; sx[lane + 64] = a1;
        }
        __syncthreads();

        float best = -INFINITY; int bi = 0;
#pragma unroll
        for (int j = 0; j < 2; ++j) {
            const int c = wv * 128 + lane + 64 * j;
            const float* cv = cbn + ((size_t)cbi * MCODES + c) * DEMB;
            float s0 = 0, s1 = 0, s2 = 0, s3 = 0;
#pragma unroll 4
            for (int k = 0; k < DEMB; k += 4) {
                const float4 xk = ld4(&sx[k]);
                const float4 ck = ld4(cv + k);
                s0 = fmaf(xk.x, ck.x, s0); s1 = fmaf(xk.y, ck.y, s1);
                s2 = fmaf(xk.z, ck.z, s2); s3 = fmaf(xk.w, ck.w, s3);
            }
            const float s = (s0 + s1) + (s2 + s3);
            if (s > best) { best = s; bi = c; }
        }
#pragma unroll
        for (int mm = 1; mm < 64; mm <<= 1) {
            const float ov = __shfl_xor(best, mm, 64);
            const int   oc = __shfl_xor(bi, mm, 64);
            if (ov > best || (ov == best && oc < bi)) { best = ov; bi = oc; }
        }
        if (lane == 0) { sBest[wv] = best; sIdx[wv] = bi; }
        __syncthreads();
        if (wv == 0 && lane == 0) {
            float b = sBest[0]; int bidx = sIdx[0];
#pragma unroll
            for (int w = 1; w < 4; ++w) {
                if (sBest[w] > b) { b = sBest[w]; bidx = sIdx[w]; }  // lower wave wins ties
            }
            out[(size_t)row * NCB + cbi] = bidx;
        }
        __syncthreads();                   // protect sx before next item
    }
}

// ---------------------------------------------------------------------------
// Fallback (ws too small): round-3 fused kernel (proven, 2 MB ws).
// ---------------------------------------------------------------------------
__global__ __launch_bounds__(256) void fused_quantize_kernel(
        const float* __restrict__ inp, const float* __restrict__ proj,
        const float* __restrict__ cbn, const unsigned short* __restrict__ cbA,
        int* __restrict__ out) {
    __shared__ float sX[128][132];
    __shared__ float sRn[128];
    const int tid = threadIdx.x;
    const int tx = tid & 31, ty = tid >> 5;
    const int rowBase = blockIdx.x * 128;

#pragma unroll 1
    for (int p = 0; p < 2; ++p) {
        float acc1[8][4];
#pragma unroll
        for (int i = 0; i < 8; ++i)
#pragma unroll
            for (int j = 0; j < 4; ++j) acc1[i][j] = 0.0f;
        const float* inRow0 = inp + (size_t)(rowBase + p * 64 + ty) * DIN;
        const float* pjCol  = proj + tx * 4;
        float4 ivA[8], ivB[8], pjA[4], pjB[4];
        auto load_step = [&](float4 iv[8], float4 pj[4], int kk) {
#pragma unroll
            for (int j = 0; j < 4; ++j) pj[j] = ld4(pjCol + (size_t)(kk + j) * DEMB);
#pragma unroll
            for (int i = 0; i < 8; ++i) iv[i] = ld4(inRow0 + (size_t)(8 * i) * DIN + kk);
        };
        auto fma_step = [&](const float4 iv[8], const float4 pj[4]) {
#pragma unroll
            for (int i = 0; i < 8; ++i) {
                const float* ivp = reinterpret_cast<const float*>(&iv[i]);
#pragma unroll
                for (int j = 0; j < 4; ++j) {
                    acc1[i][0] = fmaf(ivp[j], pj[j].x, acc1[i][0]);
                    acc1[i][1] = fmaf(ivp[j], pj[j].y, acc1[i][1]);
                    acc1[i][2] = fmaf(ivp[j], pj[j].z, acc1[i][2]);
                    acc1[i][3] = fmaf(ivp[j], pj[j].w, acc1[i][3]);
                }
            }
        };
        load_step(ivA, pjA, 0);
#pragma unroll 1
        for (int k = 0; k < DIN; k += 8) {
            load_step(ivB, pjB, k + 4);
            fma_step(ivA, pjA);
            if (k + 8 < DIN) load_step(ivA, pjA, k + 8);
            fma_step(ivB, pjB);
        }
#pragma unroll
        for (int i = 0; i < 8; ++i) {
            const int r = p * 64 + ty + 8 * i;
            float ss = acc1[i][0] * acc1[i][0] + acc1[i][1] * acc1[i][1] +
                       acc1[i][2] * acc1[i][2] + acc1[i][3] * acc1[i][3];
#pragma unroll
            for (int mm = 1; mm < 32; mm <<= 1) ss += __shfl_xor(ss, mm, 64);
            if (tx == 0) sRn[r] = 1.0f / sqrtf(ss);
            *reinterpret_cast<float4*>(&sX[r][tx * 4]) =
                make_float4(acc1[i][0], acc1[i][1], acc1[i][2], acc1[i][3]);
        }
    }
    __syncthreads();

    const int lane = tid & 63, wv = tid >> 6;
    const int kg = lane >> 5;
    const int rowL = wv * 32 + (lane & 31);
    bf16x8 Bhi[8], Blo[8];
    {
        const float rn = sRn[rowL];
#pragma unroll
        for (int kt = 0; kt < 8; ++kt) {
            const int k0 = kt * 16 + kg * 8;
            float4 f0 = ld4(&sX[rowL][k0]);
            float4 f1 = ld4(&sX[rowL][k0 + 4]);
            float xs[8] = {f0.x, f0.y, f0.z, f0.w, f1.x, f1.y, f1.z, f1.w};
            bf16x8 hv, lv;
#pragma unroll
            for (int e = 0; e < 8; ++e) {
                const float xn = xs[e] * rn;
                const unsigned short h = f2bf(xn);
                hv[e] = (short)h;
                lv[e] = (short)f2bf(xn - bf2f(h));
            }
            Bhi[kt] = hv; Blo[kt] = lv;
        }
    }
    float t1 = -INFINITY, t2 = -INFINITY; int i1 = 0;
    const short* pA = reinterpret_cast<const short*>(cbA) + (size_t)lane * 8;
#pragma unroll 1
    for (int ct = 0; ct < 64; ++ct) {
        if ((ct & 1) == 0) __syncthreads();
        const short* pct = pA + (size_t)ct * 8192;
        f32x16 accA, accB;
#pragma unroll
        for (int r = 0; r < 16; ++r) { accA[r] = 0.0f; accB[r] = 0.0f; }
#pragma unroll
        for (int kt = 0; kt < 8; ++kt) {
            const bf16x8 Ahi = *reinterpret_cast<const bf16x8*>(pct + kt * 1024);
            const bf16x8 Alo = *reinterpret_cast<const bf16x8*>(pct + kt * 1024 + 512);
            accA = __builtin_amdgcn_mfma_f32_32x32x16_bf16(Ahi, Bhi[kt], accA, 0, 0, 0);
            accB = __builtin_amdgcn_mfma_f32_32x32x16_bf16(Ahi, Blo[kt], accB, 0, 0, 0);
            accB = __builtin_amdgcn_mfma_f32_32x32x16_bf16(Alo, Bhi[kt], accB, 0, 0, 0);
        }
#pragma unroll
        for (int r = 0; r < 16; ++r) {
            const float v = accA[r] + accB[r];
            const int gidx = ct * 32 + ((r & 3) + 8 * (r >> 2) + 4 * kg);
            t2 = fmaxf(t2, fminf(v, t1));
            if (v > t1) { t1 = v; i1 = gidx; }
        }
        if ((ct & 15) == 15) {
            const int cbi = ct >> 4;
            const float o1 = __shfl_xor(t1, 32, 64);
            const float o2 = __shfl_xor(t2, 32, 64);
            const int   oi = __shfl_xor(i1, 32, 64);
            const float m2 = fmaxf(fmaxf(t2, o2), fminf(t1, o1));
            if (o1 > t1 || (o1 == t1 && oi < i1)) { t1 = o1; i1 = oi; }
            const bool unc = (t1 - m2) < MARGIN;
            if (lane < 32 && !unc)
                out[(size_t)(rowBase + rowL) * NCB + cbi] = i1 - cbi * MCODES;
            unsigned long long msk = __ballot(unc && lane < 32);
            while (msk) {
                const int r = __ffsll(msk) - 1; msk &= msk - 1;
                const int rl = wv * 32 + r;
                float best = -INFINITY; int bi = 0;
#pragma unroll 1
                for (int j = 0; j < 8; ++j) {
                    const int c = lane + 64 * j;
                    const float* cv = cbn + ((size_t)cbi * MCODES + c) * DEMB;
                    float s0 = 0, s1 = 0, s2 = 0, s3 = 0;
#pragma unroll
                    for (int k = 0; k < DEMB; k += 4) {
                        const float4 xk = ld4(&sX[rl][k]);
                        const float4 ck = ld4(cv + k);
                        s0 = fmaf(xk.x, ck.x, s0); s1 = fmaf(xk.y, ck.y, s1);
                        s2 = fmaf(xk.z, ck.z, s2); s3 = fmaf(xk.w, ck.w, s3);
                    }
                    const float s = (s0 + s1) + (s2 + s3);
                    if (s > best) { best = s; bi = c; }
                }
#pragma unroll
                for (int mm = 1; mm < 64; mm <<= 1) {
                    const float ov = __shfl_xor(best, mm, 64);
                    const int   oc = __shfl_xor(bi, mm, 64);
                    if (ov > best || (ov == best && oc < bi)) { best = ov; bi = oc; }
                }
                if (lane == 0) out[(size_t)(rowBase + rl) * NCB + cbi] = bi;
            }
            t1 = -INFINITY; t2 = -INFINITY; i1 = 0;
        }
    }
}

// ---------------------------------------------------------------------------
extern "C" void kernel_launch(void* const* d_in, const int* in_sizes, int n_in,
                              void* d_out, int out_size, void* d_ws, size_t ws_size,
                              hipStream_t stream) {
    const float* inp  = (const float*)d_in[0];   // [8,16,512,256]
    const float* proj = (const float*)d_in[1];   // [256,128]
    const float* cb   = (const float*)d_in[2];   // [4,512,128]
    int* out = (int*)d_out;                      // [8,16,512,4] int32

    char* ws = (char*)d_ws;
    float* cbn = (float*)ws;                                     // 1 MB
    unsigned short* cbA = (unsigned short*)(ws + (1 << 20));     // 1 MB
    float* xw  = (float*)(ws + (2 << 20) + (1 << 18));           // 32 MB
    const size_t off_cnt = (size_t)(2 << 20) + (1 << 18) + ((size_t)32 << 20);
    int* unc_cnt  = (int*)(ws + off_cnt);                        // 4 B (pad 256)
    int* unc_list = (int*)(ws + off_cnt + 256);                  // 1 MB
    const size_t off_pjA = off_cnt + 256 + (1 << 20);
    unsigned short* pjA = (unsigned short*)(ws + off_pjA);       // 192 KB
    const size_t need_old = off_pjA;
    const size_t need_new = off_pjA + 192 * 1024;

    hipLaunchKernelGGL(prep_codebook, dim3(NCODE / 4), dim3(256), 0, stream,
                       cb, cbn, cbA);
    if (ws_size >= need_old) {
        hipMemsetAsync(unc_cnt, 0, 4, stream);
        if (ws_size >= need_new) {
            hipLaunchKernelGGL(prep_proj, dim3(16), dim3(256), 0, stream, proj, pjA);
            hipLaunchKernelGGL(project_mfma, dim3(2048), dim3(256), 0, stream,
                               inp, pjA, xw);
        } else {
            hipLaunchKernelGGL(project_kernel, dim3(1024), dim3(256), 0, stream,
                               inp, proj, xw);
        }
        hipLaunchKernelGGL(sim_kernel, dim3(2048), dim3(256), 0, stream,
                           xw, cbA, out, unc_cnt, unc_list);
        hipLaunchKernelGGL(recheck_kernel, dim3(2048), dim3(256), 0, stream,
                           inp, proj, cbn, unc_cnt, unc_list, out);
    } else {
        hipLaunchKernelGGL(fused_quantize_kernel, dim3(512), dim3(256), 0, stream,
                           inp, proj, cbn, cbA, out);
    }
}

// Round 13
// 217.682 us; speedup vs baseline: 1.2673x; 1.0089x over previous
//
#include <hip/hip_runtime.h>
#include <math.h>

#define DIN    256
#define DEMB   128
#define NCB    4
#define MCODES 512
#define NCODE  2048
#define MARGIN 1.5e-4f      // >10x rigorous split-bf16 error bound (~1.3e-5)

using bf16x8 = __attribute__((ext_vector_type(8))) short;
using f32x16 = __attribute__((ext_vector_type(16))) float;

static __device__ __forceinline__ unsigned short f2bf(float f) {   // RNE f32->bf16
    unsigned u = __float_as_uint(f);
    u += 0x7FFFu + ((u >> 16) & 1u);
    return (unsigned short)(u >> 16);
}
static __device__ __forceinline__ float bf2f(unsigned short h) {
    return __uint_as_float(((unsigned)h) << 16);
}
static __device__ __forceinline__ float4 ld4(const float* p) {
    return *reinterpret_cast<const float4*>(p);
}
// async global->LDS DMA, 16B per lane, wave-uniform LDS base (guide §5)
static __device__ __forceinline__ void gload_lds16(const void* g, void* l) {
    __builtin_amdgcn_global_load_lds(
        (const __attribute__((address_space(1))) void*)g,
        (__attribute__((address_space(3))) void*)l, 16, 0, 0);
}

// ---------------------------------------------------------------------------
// Kernel 1: normalize codebook rows; emit (a) f32 copy for exact recheck,
// (b) hi/lo bf16 split in mfma_32x32x16 A-fragment order (tile ct = 16 KB
// contiguous: [kt 0..8][hl 0..2][lane 0..64][8 shorts]).
// ---------------------------------------------------------------------------
__global__ __launch_bounds__(256) void prep_codebook(
        const float* __restrict__ cb, float* __restrict__ cbn,
        unsigned short* __restrict__ cbA) {
    const int w = threadIdx.x >> 6, lane = threadIdx.x & 63;
    const int code = blockIdx.x * 4 + w;                 // 0..2047
    const float2 v = reinterpret_cast<const float2*>(cb + (size_t)code * DEMB)[lane];
    float ss = v.x * v.x + v.y * v.y;
#pragma unroll
    for (int m = 1; m < 64; m <<= 1) ss += __shfl_xor(ss, m, 64);
    const float rn = 1.0f / sqrtf(ss);
    const float x0 = v.x * rn, x1 = v.y * rn;
    reinterpret_cast<float2*>(cbn + (size_t)code * DEMB)[lane] = make_float2(x0, x1);

    const unsigned short h0 = f2bf(x0), h1 = f2bf(x1);
    const unsigned short l0 = f2bf(x0 - bf2f(h0)), l1 = f2bf(x1 - bf2f(h1));
    const int ct = code >> 5, ci = code & 31;
    const int kt = lane >> 3, g = (lane >> 2) & 1, i = 2 * (lane & 3);
    const size_t base = ((size_t)ct * 1024 + kt * 128 + g * 32 + ci) * 8 + i;
    *reinterpret_cast<ushort2*>(cbA + base)       = make_ushort2(h0, h1);  // hi
    *reinterpret_cast<ushort2*>(cbA + base + 512) = make_ushort2(l0, l1);  // lo
}

// ---------------------------------------------------------------------------
// Kernel 1b: 3-way split (hi/mid/lo bf16) of projector^T in A-fragment order.
// ---------------------------------------------------------------------------
__global__ __launch_bounds__(256) void prep_proj(
        const float* __restrict__ proj, unsigned short* __restrict__ pjA) {
    const int t = blockIdx.x * 256 + threadIdx.x;      // 4096 threads
    const int ci = t & 31, g = (t >> 5) & 1, kt = (t >> 6) & 15, mt = t >> 10;
    const int m = mt * 32 + ci;
    const size_t base = ((size_t)(mt * 16 + kt) * 3) * 512 + (size_t)(g * 32 + ci) * 8;
#pragma unroll
    for (int i = 0; i < 8; ++i) {
        const float v = proj[(size_t)(kt * 16 + g * 8 + i) * DEMB + m];
        const unsigned short h = f2bf(v);
        const float r1 = v - bf2f(h);                  // exact (Sterbenz)
        const unsigned short md = f2bf(r1);
        const float r2 = r1 - bf2f(md);                // exact
        pjA[base + i]        = h;
        pjA[base + 512 + i]  = md;
        pjA[base + 1024 + i] = f2bf(r2);
    }
}

// ---------------------------------------------------------------------------
// Kernel 2 (v4): projection via 6-pass split-bf16 MFMA. One mt per wave,
// no LDS/barriers, free-running; A-fragments prefetched in the 2-step
// register ping-pong alongside the input. (r12 version, kept.)
// ---------------------------------------------------------------------------
__global__ __launch_bounds__(256) void project_mfma(
        const float* __restrict__ inp, const unsigned short* __restrict__ pjA,
        float* __restrict__ xw) {
    const int tid = threadIdx.x;
    const int lane = tid & 63, mt = tid >> 6, kg = lane >> 5;
    const int row = blockIdx.x * 32 + (lane & 31);
    const float* xr = inp + (size_t)row * DIN;
    const unsigned short* pL = pjA + (size_t)lane * 8;

    auto ldin = [&](float4& a, float4& b, int kt) {
        a = ld4(xr + kt * 16 + kg * 8);
        b = ld4(xr + kt * 16 + kg * 8 + 4);
    };
    auto ldA = [&](bf16x8& h, bf16x8& m, bf16x8& l, int kt) {
        const unsigned short* pf = pL + ((size_t)(mt * 16 + kt) * 3) * 512;
        h = *reinterpret_cast<const bf16x8*>(pf);
        m = *reinterpret_cast<const bf16x8*>(pf + 512);
        l = *reinterpret_cast<const bf16x8*>(pf + 1024);
    };

    f32x16 P, Q;
#pragma unroll
    for (int r = 0; r < 16; ++r) { P[r] = 0.0f; Q[r] = 0.0f; }

    auto do_step = [&](const float4& c0, const float4& c1,
                       const bf16x8& Ah, const bf16x8& Am, const bf16x8& Al) {
        const float xs[8] = {c0.x, c0.y, c0.z, c0.w, c1.x, c1.y, c1.z, c1.w};
        bf16x8 Bh, Bm, Bl;
#pragma unroll
        for (int e = 0; e < 8; ++e) {
            const float v = xs[e];
            const unsigned short h = f2bf(v);
            const float r1 = v - bf2f(h);
            const unsigned short md = f2bf(r1);
            const float r2 = r1 - bf2f(md);
            Bh[e] = (short)h; Bm[e] = (short)md; Bl[e] = (short)f2bf(r2);
        }
        P = __builtin_amdgcn_mfma_f32_32x32x16_bf16(Ah, Bh, P, 0, 0, 0);
        Q = __builtin_amdgcn_mfma_f32_32x32x16_bf16(Ah, Bm, Q, 0, 0, 0);
        Q = __builtin_amdgcn_mfma_f32_32x32x16_bf16(Am, Bh, Q, 0, 0, 0);
        Q = __builtin_amdgcn_mfma_f32_32x32x16_bf16(Ah, Bl, Q, 0, 0, 0);
        Q = __builtin_amdgcn_mfma_f32_32x32x16_bf16(Al, Bh, Q, 0, 0, 0);
        Q = __builtin_amdgcn_mfma_f32_32x32x16_bf16(Am, Bm, Q, 0, 0, 0);
    };

    float4 iA0, iA1, iB0, iB1;
    bf16x8 hA, mA, lA, hB, mB, lB;
    ldin(iA0, iA1, 0); ldA(hA, mA, lA, 0);
    ldin(iB0, iB1, 1); ldA(hB, mB, lB, 1);

#pragma unroll 1
    for (int kt = 0; kt < 16; kt += 2) {
        do_step(iA0, iA1, hA, mA, lA);                         // step kt
        if (kt + 2 < 16) { ldin(iA0, iA1, kt + 2); ldA(hA, mA, lA, kt + 2); }
        do_step(iB0, iB1, hB, mB, lB);                         // step kt+1
        if (kt + 3 < 16) { ldin(iB0, iB1, kt + 3); ldA(hB, mB, lB, kt + 3); }
    }

#pragma unroll
    for (int q = 0; q < 4; ++q) {
        float4 v;
        v.x = P[q * 4 + 0] + Q[q * 4 + 0];
        v.y = P[q * 4 + 1] + Q[q * 4 + 1];
        v.z = P[q * 4 + 2] + Q[q * 4 + 2];
        v.w = P[q * 4 + 3] + Q[q * 4 + 3];
        *reinterpret_cast<float4*>(xw + (size_t)row * DEMB + mt * 32 + q * 8 + kg * 4) = v;
    }
}

// ---------------------------------------------------------------------------
// Kernel 2 (fallback): f32 VALU projection (exact).
// ---------------------------------------------------------------------------
__global__ __launch_bounds__(256) void project_kernel(
        const float* __restrict__ inp, const float* __restrict__ proj,
        float* __restrict__ xw) {
    const int tid = threadIdx.x, tx = tid & 31, ty = tid >> 5;
    const int rowBase = blockIdx.x * 64;

    float acc1[8][4];
#pragma unroll
    for (int i = 0; i < 8; ++i)
#pragma unroll
        for (int j = 0; j < 4; ++j) acc1[i][j] = 0.0f;

    const float* inRow0 = inp + (size_t)(rowBase + ty) * DIN;
    const float* pjCol  = proj + tx * 4;

    float4 ivA[8], ivB[8], pjA[4], pjB[4];
    auto load_step = [&](float4 iv[8], float4 pj[4], int kk) {
#pragma unroll
        for (int j = 0; j < 4; ++j) pj[j] = ld4(pjCol + (size_t)(kk + j) * DEMB);
#pragma unroll
        for (int i = 0; i < 8; ++i) iv[i] = ld4(inRow0 + (size_t)(8 * i) * DIN + kk);
    };
    auto fma_step = [&](const float4 iv[8], const float4 pj[4]) {
#pragma unroll
        for (int i = 0; i < 8; ++i) {
            const float* ivp = reinterpret_cast<const float*>(&iv[i]);
#pragma unroll
            for (int j = 0; j < 4; ++j) {
                acc1[i][0] = fmaf(ivp[j], pj[j].x, acc1[i][0]);
                acc1[i][1] = fmaf(ivp[j], pj[j].y, acc1[i][1]);
                acc1[i][2] = fmaf(ivp[j], pj[j].z, acc1[i][2]);
                acc1[i][3] = fmaf(ivp[j], pj[j].w, acc1[i][3]);
            }
        }
    };
    load_step(ivA, pjA, 0);
#pragma unroll 1
    for (int k = 0; k < DIN; k += 8) {
        load_step(ivB, pjB, k + 4);
        fma_step(ivA, pjA);
        if (k + 8 < DIN) load_step(ivA, pjA, k + 8);
        fma_step(ivB, pjB);
    }
#pragma unroll
    for (int i = 0; i < 8; ++i) {
        const int r = rowBase + ty + 8 * i;
        *reinterpret_cast<float4*>(xw + (size_t)r * DEMB + tx * 4) =
            make_float4(acc1[i][0], acc1[i][1], acc1[i][2], acc1[i][3]);
    }
}

// ---------------------------------------------------------------------------
// Kernel 3 (v8 = r10's proven v5 minus setprio): similarity + margin argmax.
// Block = (128 rows, ONE cb), grid 2048. LDS 3-buffer DMA pipeline, counted
// vmcnt(4), 1 barrier/tile, single chained acc (lowest VGPR), deferred
// epilogue. setprio REMOVED: the intrinsic pair acted as compiler sched
// fences around the dependent 24-MFMA chain, pinning the independent
// deferred-epilogue VALU outside the cluster where it could not fill the
// chain's dependency stalls (r12 lesson: m190 — setprio null-to-negative
// on non-phase-split GEMM structures).
// ---------------------------------------------------------------------------
__global__ __launch_bounds__(256) void sim_kernel(
        const float* __restrict__ xw,
        const unsigned short* __restrict__ cbA,
        int* __restrict__ out, int* __restrict__ unc_cnt,
        int* __restrict__ unc_list) {
    __shared__ __align__(16) short sA[3][8192];   // 3 x 16 KB tile buffers
    const int tid = threadIdx.x;
    const int lane = tid & 63, wv = tid >> 6;     // wv 0..3
    const int kg = lane >> 5;
    const int cbi = blockIdx.x & 3;
    const int rowBase = (blockIdx.x >> 2) * 128;
    const int row = rowBase + wv * 32 + (lane & 31);

    const short* gA = (const short*)cbA + (size_t)cbi * 16 * 8192;
    auto stage = [&](int buf, int t) {   // 16 KB tile, 4 DMA instrs/thread
        const short* g = gA + (size_t)t * 8192 + wv * 2048 + lane * 8;
        short* l = &sA[buf][wv * 2048];
#pragma unroll
        for (int c = 0; c < 4; ++c)
            gload_lds16(g + c * 512, l + c * 512);
    };

    stage(0, 0);
    stage(1, 1);

    // B-frag hoist with INLINE norm: load raw x, ss-reduce, split hi/lo.
    bf16x8 Bhi[8], Blo[8];
    {
        const float* xr = xw + (size_t)row * DEMB;
        float4 f0[8], f1[8];
        float ss = 0.0f;
#pragma unroll
        for (int kt = 0; kt < 8; ++kt) {
            f0[kt] = ld4(xr + kt * 16 + kg * 8);
            f1[kt] = ld4(xr + kt * 16 + kg * 8 + 4);
            ss += f0[kt].x * f0[kt].x + f0[kt].y * f0[kt].y +
                  f0[kt].z * f0[kt].z + f0[kt].w * f0[kt].w +
                  f1[kt].x * f1[kt].x + f1[kt].y * f1[kt].y +
                  f1[kt].z * f1[kt].z + f1[kt].w * f1[kt].w;
        }
        ss += __shfl_xor(ss, 32, 64);      // partner kg-half, same row
        const float rn = 1.0f / sqrtf(ss);
#pragma unroll
        for (int kt = 0; kt < 8; ++kt) {
            const float xs[8] = {f0[kt].x, f0[kt].y, f0[kt].z, f0[kt].w,
                                 f1[kt].x, f1[kt].y, f1[kt].z, f1[kt].w};
            bf16x8 hv, lv;
#pragma unroll
            for (int e = 0; e < 8; ++e) {
                const float xn = xs[e] * rn;
                const unsigned short h = f2bf(xn);
                hv[e] = (short)h;
                lv[e] = (short)f2bf(xn - bf2f(h));
            }
            Bhi[kt] = hv; Blo[kt] = lv;
        }
    }

    f32x16 TWO;
#pragma unroll
    for (int r = 0; r < 16; ++r) TWO[r] = 2.0f;

    f32x16 acc = TWO;                      // g=0 pAcc is unused (defined value)
    float t1 = -INFINITY, t2 = -INFINITY; int i1 = 0;

#pragma unroll 1
    for (int g = 0; g < 16; ++g) {
        if (g < 15) asm volatile("s_waitcnt vmcnt(4)" ::: "memory");
        else        asm volatile("s_waitcnt vmcnt(0)" ::: "memory");
        __builtin_amdgcn_s_barrier();
        asm volatile("" ::: "memory");
        if (g + 2 < 16) stage((g + 2) % 3, g + 2);

        const short* pa = &sA[g % 3][lane * 8];
        const f32x16 pAcc = acc;           // tile g-1 result (rename)
#pragma unroll
        for (int kt = 0; kt < 8; ++kt) {   // single chained acc (24 MFMA)
            const bf16x8 Ahi = *reinterpret_cast<const bf16x8*>(pa + kt * 1024);
            const bf16x8 Alo = *reinterpret_cast<const bf16x8*>(pa + kt * 1024 + 512);
            acc = __builtin_amdgcn_mfma_f32_32x32x16_bf16(Ahi, Bhi[kt], kt ? acc : TWO, 0, 0, 0);
            acc = __builtin_amdgcn_mfma_f32_32x32x16_bf16(Ahi, Blo[kt], acc, 0, 0, 0);
            acc = __builtin_amdgcn_mfma_f32_32x32x16_bf16(Alo, Bhi[kt], acc, 0, 0, 0);
        }

        if (g > 0) {                       // deferred top-2 of tile g-1:
            const int base = (g - 1) * 32; // independent of the chain above,
#pragma unroll                              // free to interleave into stalls
            for (int r = 0; r < 16; ++r) {
                const float v = pAcc[r];
                const int gidx = base + (r & 3) + 8 * (r >> 2) + 4 * kg;
                t2 = fmaxf(t2, fminf(v, t1));
                if (v > t1) { t1 = v; i1 = gidx; }
            }
        }
    }
    {                                      // drain: tile 15
        const int base = 15 * 32;
#pragma unroll
        for (int r = 0; r < 16; ++r) {
            const float v = acc[r];
            const int gidx = base + (r & 3) + 8 * (r >> 2) + 4 * kg;
            t2 = fmaxf(t2, fminf(v, t1));
            if (v > t1) { t1 = v; i1 = gidx; }
        }
    }

    // merge kg halves (lane L <-> L^32: same row, disjoint codes)
    const float o1 = __shfl_xor(t1, 32, 64);
    const float o2 = __shfl_xor(t2, 32, 64);
    const int   oi = __shfl_xor(i1, 32, 64);
    const float m2 = fmaxf(fmaxf(t2, o2), fminf(t1, o1));
    if (o1 > t1 || (o1 == t1 && oi < i1)) { t1 = o1; i1 = oi; }
    const bool unc = (t1 - m2) < MARGIN;
    if (lane < 32 && !unc)
        out[(size_t)row * NCB + cbi] = i1;

    unsigned long long msk = __ballot(unc && lane < 32);
    if (lane == 0 && msk) {
        const int n = __popcll(msk);
        int base = atomicAdd(unc_cnt, n);
        while (msk) {
            const int r = __ffsll(msk) - 1; msk &= msk - 1;
            unc_list[base++] = ((rowBase + wv * 32 + r) << 2) | cbi;
        }
    }
}

// ---------------------------------------------------------------------------
// Kernel 4 (v2): exact recheck, ONE BLOCK PER ITEM (grid-stride). Wave 0
// recomputes x exactly (f32 inp@proj); after barrier the 4 waves scan 128
// codes each; per-wave first-max reduce, LDS merge preferring lower wave
// (wave code-ranges disjoint ascending => first-max semantics). (r12, kept.)
// ---------------------------------------------------------------------------
__global__ __launch_bounds__(256) void recheck_kernel(
        const float* __restrict__ inp, const float* __restrict__ proj,
        const float* __restrict__ cbn,
        const int* __restrict__ unc_cnt, const int* __restrict__ unc_list,
        int* __restrict__ out) {
    __shared__ float sx[DEMB];
    __shared__ float sBest[4];
    __shared__ int   sIdx[4];
    const int lane = threadIdx.x & 63, wv = threadIdx.x >> 6;
    const int n = *unc_cnt;
    for (int it = blockIdx.x; it < n; it += gridDim.x) {
        const int item = unc_list[it];
        const int row = item >> 2, cbi = item & 3;
        if (wv == 0) {                     // exact x: lane owns cols lane,lane+64
            const float* ir = inp + (size_t)row * DIN;
            float a0 = 0.0f, a1 = 0.0f;
#pragma unroll 2
            for (int k = 0; k < DIN; k += 4) {
                const float4 iv = ld4(ir + k);
                const float* ivp = reinterpret_cast<const float*>(&iv);
#pragma unroll
                for (int j = 0; j < 4; ++j) {
                    a0 = fmaf(ivp[j], proj[(size_t)(k + j) * DEMB + lane],      a0);
                    a1 = fmaf(ivp[j], proj[(size_t)(k + j) * DEMB + lane + 64], a1);
                }
            }
            sx[lane] = a0; sx[lane + 64] = a1;
        }
        __syncthreads();

        float best = -INFINITY; int bi = 0;
#pragma unroll
        for (int j = 0; j < 2; ++j) {
            const int c = wv * 128 + lane + 64 * j;
            const float* cv = cbn + ((size_t)cbi * MCODES + c) * DEMB;
            float s0 = 0, s1 = 0, s2 = 0, s3 = 0;
#pragma unroll 4
            for (int k = 0; k < DEMB; k += 4) {
                const float4 xk = ld4(&sx[k]);
                const float4 ck = ld4(cv + k);
                s0 = fmaf(xk.x, ck.x, s0); s1 = fmaf(xk.y, ck.y, s1);
                s2 = fmaf(xk.z, ck.z, s2); s3 = fmaf(xk.w, ck.w, s3);
            }
            const float s = (s0 + s1) + (s2 + s3);
            if (s > best) { best = s; bi = c; }
        }
#pragma unroll
        for (int mm = 1; mm < 64; mm <<= 1) {
            const float ov = __shfl_xor(best, mm, 64);
            const int   oc = __shfl_xor(bi, mm, 64);
            if (ov > best || (ov == best && oc < bi)) { best = ov; bi = oc; }
        }
        if (lane == 0) { sBest[wv] = best; sIdx[wv] = bi; }
        __syncthreads();
        if (wv == 0 && lane == 0) {
            float b = sBest[0]; int bidx = sIdx[0];
#pragma unroll
            for (int w = 1; w < 4; ++w) {
                if (sBest[w] > b) { b = sBest[w]; bidx = sIdx[w]; }  // lower wave wins ties
            }
            out[(size_t)row * NCB + cbi] = bidx;
        }
        __syncthreads();                   // protect sx before next item
    }
}

// ---------------------------------------------------------------------------
// Fallback (ws too small): round-3 fused kernel (proven, 2 MB ws).
// ---------------------------------------------------------------------------
__global__ __launch_bounds__(256) void fused_quantize_kernel(
        const float* __restrict__ inp, const float* __restrict__ proj,
        const float* __restrict__ cbn, const unsigned short* __restrict__ cbA,
        int* __restrict__ out) {
    __shared__ float sX[128][132];
    __shared__ float sRn[128];
    const int tid = threadIdx.x;
    const int tx = tid & 31, ty = tid >> 5;
    const int rowBase = blockIdx.x * 128;

#pragma unroll 1
    for (int p = 0; p < 2; ++p) {
        float acc1[8][4];
#pragma unroll
        for (int i = 0; i < 8; ++i)
#pragma unroll
            for (int j = 0; j < 4; ++j) acc1[i][j] = 0.0f;
        const float* inRow0 = inp + (size_t)(rowBase + p * 64 + ty) * DIN;
        const float* pjCol  = proj + tx * 4;
        float4 ivA[8], ivB[8], pjA[4], pjB[4];
        auto load_step = [&](float4 iv[8], float4 pj[4], int kk) {
#pragma unroll
            for (int j = 0; j < 4; ++j) pj[j] = ld4(pjCol + (size_t)(kk + j) * DEMB);
#pragma unroll
            for (int i = 0; i < 8; ++i) iv[i] = ld4(inRow0 + (size_t)(8 * i) * DIN + kk);
        };
        auto fma_step = [&](const float4 iv[8], const float4 pj[4]) {
#pragma unroll
            for (int i = 0; i < 8; ++i) {
                const float* ivp = reinterpret_cast<const float*>(&iv[i]);
#pragma unroll
                for (int j = 0; j < 4; ++j) {
                    acc1[i][0] = fmaf(ivp[j], pj[j].x, acc1[i][0]);
                    acc1[i][1] = fmaf(ivp[j], pj[j].y, acc1[i][1]);
                    acc1[i][2] = fmaf(ivp[j], pj[j].z, acc1[i][2]);
                    acc1[i][3] = fmaf(ivp[j], pj[j].w, acc1[i][3]);
                }
            }
        };
        load_step(ivA, pjA, 0);
#pragma unroll 1
        for (int k = 0; k < DIN; k += 8) {
            load_step(ivB, pjB, k + 4);
            fma_step(ivA, pjA);
            if (k + 8 < DIN) load_step(ivA, pjA, k + 8);
            fma_step(ivB, pjB);
        }
#pragma unroll
        for (int i = 0; i < 8; ++i) {
            const int r = p * 64 + ty + 8 * i;
            float ss = acc1[i][0] * acc1[i][0] + acc1[i][1] * acc1[i][1] +
                       acc1[i][2] * acc1[i][2] + acc1[i][3] * acc1[i][3];
#pragma unroll
            for (int mm = 1; mm < 32; mm <<= 1) ss += __shfl_xor(ss, mm, 64);
            if (tx == 0) sRn[r] = 1.0f / sqrtf(ss);
            *reinterpret_cast<float4*>(&sX[r][tx * 4]) =
                make_float4(acc1[i][0], acc1[i][1], acc1[i][2], acc1[i][3]);
        }
    }
    __syncthreads();

    const int lane = tid & 63, wv = tid >> 6;
    const int kg = lane >> 5;
    const int rowL = wv * 32 + (lane & 31);
    bf16x8 Bhi[8], Blo[8];
    {
        const float rn = sRn[rowL];
#pragma unroll
        for (int kt = 0; kt < 8; ++kt) {
            const int k0 = kt * 16 + kg * 8;
            float4 f0 = ld4(&sX[rowL][k0]);
            float4 f1 = ld4(&sX[rowL][k0 + 4]);
            float xs[8] = {f0.x, f0.y, f0.z, f0.w, f1.x, f1.y, f1.z, f1.w};
            bf16x8 hv, lv;
#pragma unroll
            for (int e = 0; e < 8; ++e) {
                const float xn = xs[e] * rn;
                const unsigned short h = f2bf(xn);
                hv[e] = (short)h;
                lv[e] = (short)f2bf(xn - bf2f(h));
            }
            Bhi[kt] = hv; Blo[kt] = lv;
        }
    }
    float t1 = -INFINITY, t2 = -INFINITY; int i1 = 0;
    const short* pA = reinterpret_cast<const short*>(cbA) + (size_t)lane * 8;
#pragma unroll 1
    for (int ct = 0; ct < 64; ++ct) {
        if ((ct & 1) == 0) __syncthreads();
        const short* pct = pA + (size_t)ct * 8192;
        f32x16 accA, accB;
#pragma unroll
        for (int r = 0; r < 16; ++r) { accA[r] = 0.0f; accB[r] = 0.0f; }
#pragma unroll
        for (int kt = 0; kt < 8; ++kt) {
            const bf16x8 Ahi = *reinterpret_cast<const bf16x8*>(pct + kt * 1024);
            const bf16x8 Alo = *reinterpret_cast<const bf16x8*>(pct + kt * 1024 + 512);
            accA = __builtin_amdgcn_mfma_f32_32x32x16_bf16(Ahi, Bhi[kt], accA, 0, 0, 0);
            accB = __builtin_amdgcn_mfma_f32_32x32x16_bf16(Ahi, Blo[kt], accB, 0, 0, 0);
            accB = __builtin_amdgcn_mfma_f32_32x32x16_bf16(Alo, Bhi[kt], accB, 0, 0, 0);
        }
#pragma unroll
        for (int r = 0; r < 16; ++r) {
            const float v = accA[r] + accB[r];
            const int gidx = ct * 32 + ((r & 3) + 8 * (r >> 2) + 4 * kg);
            t2 = fmaxf(t2, fminf(v, t1));
            if (v > t1) { t1 = v; i1 = gidx; }
        }
        if ((ct & 15) == 15) {
            const int cbi = ct >> 4;
            const float o1 = __shfl_xor(t1, 32, 64);
            const float o2 = __shfl_xor(t2, 32, 64);
            const int   oi = __shfl_xor(i1, 32, 64);
            const float m2 = fmaxf(fmaxf(t2, o2), fminf(t1, o1));
            if (o1 > t1 || (o1 == t1 && oi < i1)) { t1 = o1; i1 = oi; }
            const bool unc = (t1 - m2) < MARGIN;
            if (lane < 32 && !unc)
                out[(size_t)(rowBase + rowL) * NCB + cbi] = i1 - cbi * MCODES;
            unsigned long long msk = __ballot(unc && lane < 32);
            while (msk) {
                const int r = __ffsll(msk) - 1; msk &= msk - 1;
                const int rl = wv * 32 + r;
                float best = -INFINITY; int bi = 0;
#pragma unroll 1
                for (int j = 0; j < 8; ++j) {
                    const int c = lane + 64 * j;
                    const float* cv = cbn + ((size_t)cbi * MCODES + c) * DEMB;
                    float s0 = 0, s1 = 0, s2 = 0, s3 = 0;
#pragma unroll
                    for (int k = 0; k < DEMB; k += 4) {
                        const float4 xk = ld4(&sX[rl][k]);
                        const float4 ck = ld4(cv + k);
                        s0 = fmaf(xk.x, ck.x, s0); s1 = fmaf(xk.y, ck.y, s1);
                        s2 = fmaf(xk.z, ck.z, s2); s3 = fmaf(xk.w, ck.w, s3);
                    }
                    const float s = (s0 + s1) + (s2 + s3);
                    if (s > best) { best = s; bi = c; }
                }
#pragma unroll
                for (int mm = 1; mm < 64; mm <<= 1) {
                    const float ov = __shfl_xor(best, mm, 64);
                    const int   oc = __shfl_xor(bi, mm, 64);
                    if (ov > best || (ov == best && oc < bi)) { best = ov; bi = oc; }
                }
                if (lane == 0) out[(size_t)(rowBase + rl) * NCB + cbi] = bi;
            }
            t1 = -INFINITY; t2 = -INFINITY; i1 = 0;
        }
    }
}

// ---------------------------------------------------------------------------
extern "C" void kernel_launch(void* const* d_in, const int* in_sizes, int n_in,
                              void* d_out, int out_size, void* d_ws, size_t ws_size,
                              hipStream_t stream) {
    const float* inp  = (const float*)d_in[0];   // [8,16,512,256]
    const float* proj = (const float*)d_in[1];   // [256,128]
    const float* cb   = (const float*)d_in[2];   // [4,512,128]
    int* out = (int*)d_out;                      // [8,16,512,4] int32

    char* ws = (char*)d_ws;
    float* cbn = (float*)ws;                                     // 1 MB
    unsigned short* cbA = (unsigned short*)(ws + (1 << 20));     // 1 MB
    float* xw  = (float*)(ws + (2 << 20) + (1 << 18));           // 32 MB
    const size_t off_cnt = (size_t)(2 << 20) + (1 << 18) + ((size_t)32 << 20);
    int* unc_cnt  = (int*)(ws + off_cnt);                        // 4 B (pad 256)
    int* unc_list = (int*)(ws + off_cnt + 256);                  // 1 MB
    const size_t off_pjA = off_cnt + 256 + (1 << 20);
    unsigned short* pjA = (unsigned short*)(ws + off_pjA);       // 192 KB
    const size_t need_old = off_pjA;
    const size_t need_new = off_pjA + 192 * 1024;

    hipLaunchKernelGGL(prep_codebook, dim3(NCODE / 4), dim3(256), 0, stream,
                       cb, cbn, cbA);
    if (ws_size >= need_old) {
        hipMemsetAsync(unc_cnt, 0, 4, stream);
        if (ws_size >= need_new) {
            hipLaunchKernelGGL(prep_proj, dim3(16), dim3(256), 0, stream, proj, pjA);
            hipLaunchKernelGGL(project_mfma, dim3(2048), dim3(256), 0, stream,
                               inp, pjA, xw);
        } else {
            hipLaunchKernelGGL(project_kernel, dim3(1024), dim3(256), 0, stream,
                               inp, proj, xw);
        }
        hipLaunchKernelGGL(sim_kernel, dim3(2048), dim3(256), 0, stream,
                           xw, cbA, out, unc_cnt, unc_list);
        hipLaunchKernelGGL(recheck_kernel, dim3(2048), dim3(256), 0, stream,
                           inp, proj, cbn, unc_cnt, unc_list, out);
    } else {
        hipLaunchKernelGGL(fused_quantize_kernel, dim3(512), dim3(256), 0, stream,
                           inp, proj, cbn, cbA, out);
    }
}

// Round 14
// 210.876 us; speedup vs baseline: 1.3082x; 1.0323x over previous
//
#include <hip/hip_runtime.h>
#include <math.h>

#define DIN    256
#define DEMB   128
#define NCB    4
#define MCODES 512
#define NCODE  2048
#define MARGIN 1.5e-4f      // split-bf16 bound 1.3e-5 + 4-bit key quant 7.6e-6; 7x headroom

using bf16x8 = __attribute__((ext_vector_type(8))) short;
using f32x16 = __attribute__((ext_vector_type(16))) float;

static __device__ __forceinline__ unsigned short f2bf(float f) {   // RNE f32->bf16
    unsigned u = __float_as_uint(f);
    u += 0x7FFFu + ((u >> 16) & 1u);
    return (unsigned short)(u >> 16);
}
static __device__ __forceinline__ float bf2f(unsigned short h) {
    return __uint_as_float(((unsigned)h) << 16);
}
static __device__ __forceinline__ float4 ld4(const float* p) {
    return *reinterpret_cast<const float4*>(p);
}
static __device__ __forceinline__ unsigned umaxu(unsigned a, unsigned b) { return a > b ? a : b; }
static __device__ __forceinline__ unsigned uminu(unsigned a, unsigned b) { return a < b ? a : b; }
// async global->LDS DMA, 16B per lane, wave-uniform LDS base (guide §5)
static __device__ __forceinline__ void gload_lds16(const void* g, void* l) {
    __builtin_amdgcn_global_load_lds(
        (const __attribute__((address_space(1))) void*)g,
        (__attribute__((address_space(3))) void*)l, 16, 0, 0);
}

// ---------------------------------------------------------------------------
// Kernel 1: normalize codebook rows; emit (a) f32 copy for exact recheck,
// (b) hi/lo bf16 split in mfma_32x32x16 A-fragment order (tile ct = 16 KB
// contiguous: [kt 0..8][hl 0..2][lane 0..64][8 shorts]).
// ---------------------------------------------------------------------------
__global__ __launch_bounds__(256) void prep_codebook(
        const float* __restrict__ cb, float* __restrict__ cbn,
        unsigned short* __restrict__ cbA) {
    const int w = threadIdx.x >> 6, lane = threadIdx.x & 63;
    const int code = blockIdx.x * 4 + w;                 // 0..2047
    const float2 v = reinterpret_cast<const float2*>(cb + (size_t)code * DEMB)[lane];
    float ss = v.x * v.x + v.y * v.y;
#pragma unroll
    for (int m = 1; m < 64; m <<= 1) ss += __shfl_xor(ss, m, 64);
    const float rn = 1.0f / sqrtf(ss);
    const float x0 = v.x * rn, x1 = v.y * rn;
    reinterpret_cast<float2*>(cbn + (size_t)code * DEMB)[lane] = make_float2(x0, x1);

    const unsigned short h0 = f2bf(x0), h1 = f2bf(x1);
    const unsigned short l0 = f2bf(x0 - bf2f(h0)), l1 = f2bf(x1 - bf2f(h1));
    const int ct = code >> 5, ci = code & 31;
    const int kt = lane >> 3, g = (lane >> 2) & 1, i = 2 * (lane & 3);
    const size_t base = ((size_t)ct * 1024 + kt * 128 + g * 32 + ci) * 8 + i;
    *reinterpret_cast<ushort2*>(cbA + base)       = make_ushort2(h0, h1);  // hi
    *reinterpret_cast<ushort2*>(cbA + base + 512) = make_ushort2(l0, l1);  // lo
}

// ---------------------------------------------------------------------------
// Kernel 1b: 3-way split (hi/mid/lo bf16) of projector^T in A-fragment order.
// ---------------------------------------------------------------------------
__global__ __launch_bounds__(256) void prep_proj(
        const float* __restrict__ proj, unsigned short* __restrict__ pjA) {
    const int t = blockIdx.x * 256 + threadIdx.x;      // 4096 threads
    const int ci = t & 31, g = (t >> 5) & 1, kt = (t >> 6) & 15, mt = t >> 10;
    const int m = mt * 32 + ci;
    const size_t base = ((size_t)(mt * 16 + kt) * 3) * 512 + (size_t)(g * 32 + ci) * 8;
#pragma unroll
    for (int i = 0; i < 8; ++i) {
        const float v = proj[(size_t)(kt * 16 + g * 8 + i) * DEMB + m];
        const unsigned short h = f2bf(v);
        const float r1 = v - bf2f(h);                  // exact (Sterbenz)
        const unsigned short md = f2bf(r1);
        const float r2 = r1 - bf2f(md);                // exact
        pjA[base + i]        = h;
        pjA[base + 512 + i]  = md;
        pjA[base + 1024 + i] = f2bf(r2);
    }
}

// ---------------------------------------------------------------------------
// Kernel 2 (v4): projection via 6-pass split-bf16 MFMA. One mt per wave,
// no LDS/barriers, free-running; A-fragments prefetched in the 2-step
// register ping-pong alongside the input. (r12 version, kept.)
// ---------------------------------------------------------------------------
__global__ __launch_bounds__(256) void project_mfma(
        const float* __restrict__ inp, const unsigned short* __restrict__ pjA,
        float* __restrict__ xw) {
    const int tid = threadIdx.x;
    const int lane = tid & 63, mt = tid >> 6, kg = lane >> 5;
    const int row = blockIdx.x * 32 + (lane & 31);
    const float* xr = inp + (size_t)row * DIN;
    const unsigned short* pL = pjA + (size_t)lane * 8;

    auto ldin = [&](float4& a, float4& b, int kt) {
        a = ld4(xr + kt * 16 + kg * 8);
        b = ld4(xr + kt * 16 + kg * 8 + 4);
    };
    auto ldA = [&](bf16x8& h, bf16x8& m, bf16x8& l, int kt) {
        const unsigned short* pf = pL + ((size_t)(mt * 16 + kt) * 3) * 512;
        h = *reinterpret_cast<const bf16x8*>(pf);
        m = *reinterpret_cast<const bf16x8*>(pf + 512);
        l = *reinterpret_cast<const bf16x8*>(pf + 1024);
    };

    f32x16 P, Q;
#pragma unroll
    for (int r = 0; r < 16; ++r) { P[r] = 0.0f; Q[r] = 0.0f; }

    auto do_step = [&](const float4& c0, const float4& c1,
                       const bf16x8& Ah, const bf16x8& Am, const bf16x8& Al) {
        const float xs[8] = {c0.x, c0.y, c0.z, c0.w, c1.x, c1.y, c1.z, c1.w};
        bf16x8 Bh, Bm, Bl;
#pragma unroll
        for (int e = 0; e < 8; ++e) {
            const float v = xs[e];
            const unsigned short h = f2bf(v);
            const float r1 = v - bf2f(h);
            const unsigned short md = f2bf(r1);
            const float r2 = r1 - bf2f(md);
            Bh[e] = (short)h; Bm[e] = (short)md; Bl[e] = (short)f2bf(r2);
        }
        P = __builtin_amdgcn_mfma_f32_32x32x16_bf16(Ah, Bh, P, 0, 0, 0);
        Q = __builtin_amdgcn_mfma_f32_32x32x16_bf16(Ah, Bm, Q, 0, 0, 0);
        Q = __builtin_amdgcn_mfma_f32_32x32x16_bf16(Am, Bh, Q, 0, 0, 0);
        Q = __builtin_amdgcn_mfma_f32_32x32x16_bf16(Ah, Bl, Q, 0, 0, 0);
        Q = __builtin_amdgcn_mfma_f32_32x32x16_bf16(Al, Bh, Q, 0, 0, 0);
        Q = __builtin_amdgcn_mfma_f32_32x32x16_bf16(Am, Bm, Q, 0, 0, 0);
    };

    float4 iA0, iA1, iB0, iB1;
    bf16x8 hA, mA, lA, hB, mB, lB;
    ldin(iA0, iA1, 0); ldA(hA, mA, lA, 0);
    ldin(iB0, iB1, 1); ldA(hB, mB, lB, 1);

#pragma unroll 1
    for (int kt = 0; kt < 16; kt += 2) {
        do_step(iA0, iA1, hA, mA, lA);                         // step kt
        if (kt + 2 < 16) { ldin(iA0, iA1, kt + 2); ldA(hA, mA, lA, kt + 2); }
        do_step(iB0, iB1, hB, mB, lB);                         // step kt+1
        if (kt + 3 < 16) { ldin(iB0, iB1, kt + 3); ldA(hB, mB, lB, kt + 3); }
    }

#pragma unroll
    for (int q = 0; q < 4; ++q) {
        float4 v;
        v.x = P[q * 4 + 0] + Q[q * 4 + 0];
        v.y = P[q * 4 + 1] + Q[q * 4 + 1];
        v.z = P[q * 4 + 2] + Q[q * 4 + 2];
        v.w = P[q * 4 + 3] + Q[q * 4 + 3];
        *reinterpret_cast<float4*>(xw + (size_t)row * DEMB + mt * 32 + q * 8 + kg * 4) = v;
    }
}

// ---------------------------------------------------------------------------
// Kernel 2 (fallback): f32 VALU projection (exact).
// ---------------------------------------------------------------------------
__global__ __launch_bounds__(256) void project_kernel(
        const float* __restrict__ inp, const float* __restrict__ proj,
        float* __restrict__ xw) {
    const int tid = threadIdx.x, tx = tid & 31, ty = tid >> 5;
    const int rowBase = blockIdx.x * 64;

    float acc1[8][4];
#pragma unroll
    for (int i = 0; i < 8; ++i)
#pragma unroll
        for (int j = 0; j < 4; ++j) acc1[i][j] = 0.0f;

    const float* inRow0 = inp + (size_t)(rowBase + ty) * DIN;
    const float* pjCol  = proj + tx * 4;

    float4 ivA[8], ivB[8], pjA[4], pjB[4];
    auto load_step = [&](float4 iv[8], float4 pj[4], int kk) {
#pragma unroll
        for (int j = 0; j < 4; ++j) pj[j] = ld4(pjCol + (size_t)(kk + j) * DEMB);
#pragma unroll
        for (int i = 0; i < 8; ++i) iv[i] = ld4(inRow0 + (size_t)(8 * i) * DIN + kk);
    };
    auto fma_step = [&](const float4 iv[8], const float4 pj[4]) {
#pragma unroll
        for (int i = 0; i < 8; ++i) {
            const float* ivp = reinterpret_cast<const float*>(&iv[i]);
#pragma unroll
            for (int j = 0; j < 4; ++j) {
                acc1[i][0] = fmaf(ivp[j], pj[j].x, acc1[i][0]);
                acc1[i][1] = fmaf(ivp[j], pj[j].y, acc1[i][1]);
                acc1[i][2] = fmaf(ivp[j], pj[j].z, acc1[i][2]);
                acc1[i][3] = fmaf(ivp[j], pj[j].w, acc1[i][3]);
            }
        }
    };
    load_step(ivA, pjA, 0);
#pragma unroll 1
    for (int k = 0; k < DIN; k += 8) {
        load_step(ivB, pjB, k + 4);
        fma_step(ivA, pjA);
        if (k + 8 < DIN) load_step(ivA, pjA, k + 8);
        fma_step(ivB, pjB);
    }
#pragma unroll
    for (int i = 0; i < 8; ++i) {
        const int r = rowBase + ty + 8 * i;
        *reinterpret_cast<float4*>(xw + (size_t)r * DEMB + tx * 4) =
            make_float4(acc1[i][0], acc1[i][1], acc1[i][2], acc1[i][3]);
    }
}

// ---------------------------------------------------------------------------
// Kernel 3 (v9 = r13 skeleton + compact packed-key epilogue): similarity +
// margin argmax. Block = (128 rows, ONE cb), grid 2048. LDS 3-buffer DMA
// pipeline, counted vmcnt(4), 1 barrier/tile, single chained acc, deferred
// epilogue. NEW: top-2 via 28-bit float key | 4-bit rank (r8 redux with
// only 4 truncated bits -> quantization 7.6e-6, MARGIN unchanged 1.5e-4):
// per value 4 u32 ops (and_or, umin, umax, umax), no index cndmasks;
// winning TILE tracked once per tile (t1k-changed check). Equal keys /
// cross-tile ties give gap<=0 -> uncertain -> exact recheck (first-max
// semantics preserved; rank field descending in r makes lower code win
// within-tile ties).
// ---------------------------------------------------------------------------
__global__ __launch_bounds__(256) void sim_kernel(
        const float* __restrict__ xw,
        const unsigned short* __restrict__ cbA,
        int* __restrict__ out, int* __restrict__ unc_cnt,
        int* __restrict__ unc_list) {
    __shared__ __align__(16) short sA[3][8192];   // 3 x 16 KB tile buffers
    const int tid = threadIdx.x;
    const int lane = tid & 63, wv = tid >> 6;     // wv 0..3
    const int kg = lane >> 5;
    const int cbi = blockIdx.x & 3;
    const int rowBase = (blockIdx.x >> 2) * 128;
    const int row = rowBase + wv * 32 + (lane & 31);

    const short* gA = (const short*)cbA + (size_t)cbi * 16 * 8192;
    auto stage = [&](int buf, int t) {   // 16 KB tile, 4 DMA instrs/thread
        const short* g = gA + (size_t)t * 8192 + wv * 2048 + lane * 8;
        short* l = &sA[buf][wv * 2048];
#pragma unroll
        for (int c = 0; c < 4; ++c)
            gload_lds16(g + c * 512, l + c * 512);
    };

    stage(0, 0);
    stage(1, 1);

    // B-frag hoist with INLINE norm: load raw x, ss-reduce, split hi/lo.
    bf16x8 Bhi[8], Blo[8];
    {
        const float* xr = xw + (size_t)row * DEMB;
        float4 f0[8], f1[8];
        float ss = 0.0f;
#pragma unroll
        for (int kt = 0; kt < 8; ++kt) {
            f0[kt] = ld4(xr + kt * 16 + kg * 8);
            f1[kt] = ld4(xr + kt * 16 + kg * 8 + 4);
            ss += f0[kt].x * f0[kt].x + f0[kt].y * f0[kt].y +
                  f0[kt].z * f0[kt].z + f0[kt].w * f0[kt].w +
                  f1[kt].x * f1[kt].x + f1[kt].y * f1[kt].y +
                  f1[kt].z * f1[kt].z + f1[kt].w * f1[kt].w;
        }
        ss += __shfl_xor(ss, 32, 64);      // partner kg-half, same row
        const float rn = 1.0f / sqrtf(ss);
#pragma unroll
        for (int kt = 0; kt < 8; ++kt) {
            const float xs[8] = {f0[kt].x, f0[kt].y, f0[kt].z, f0[kt].w,
                                 f1[kt].x, f1[kt].y, f1[kt].z, f1[kt].w};
            bf16x8 hv, lv;
#pragma unroll
            for (int e = 0; e < 8; ++e) {
                const float xn = xs[e] * rn;
                const unsigned short h = f2bf(xn);
                hv[e] = (short)h;
                lv[e] = (short)f2bf(xn - bf2f(h));
            }
            Bhi[kt] = hv; Blo[kt] = lv;
        }
    }

    f32x16 TWO;
#pragma unroll
    for (int r = 0; r < 16; ++r) TWO[r] = 2.0f;

    f32x16 acc = TWO;                      // g=0 pAcc is unused (defined value)
    unsigned t1k = 0u, t2k = 0u; int btile = 0;

    auto epi = [&](const f32x16& pAcc, int gprev) {
        const unsigned prev = t1k;
#pragma unroll
        for (int r = 0; r < 16; ++r) {     // 4 u32 ops/value
            const unsigned kb = (__float_as_uint(pAcc[r]) & 0xFFFFFFF0u) | (15u - (unsigned)r);
            t2k = umaxu(t2k, uminu(kb, t1k));
            t1k = umaxu(t1k, kb);
        }
        if (t1k != prev) btile = gprev;    // once per tile
    };

#pragma unroll 1
    for (int g = 0; g < 16; ++g) {
        if (g < 15) asm volatile("s_waitcnt vmcnt(4)" ::: "memory");
        else        asm volatile("s_waitcnt vmcnt(0)" ::: "memory");
        __builtin_amdgcn_s_barrier();
        asm volatile("" ::: "memory");
        if (g + 2 < 16) stage((g + 2) % 3, g + 2);

        const short* pa = &sA[g % 3][lane * 8];
        const f32x16 pAcc = acc;           // tile g-1 result (rename)
#pragma unroll
        for (int kt = 0; kt < 8; ++kt) {   // single chained acc (24 MFMA)
            const bf16x8 Ahi = *reinterpret_cast<const bf16x8*>(pa + kt * 1024);
            const bf16x8 Alo = *reinterpret_cast<const bf16x8*>(pa + kt * 1024 + 512);
            acc = __builtin_amdgcn_mfma_f32_32x32x16_bf16(Ahi, Bhi[kt], kt ? acc : TWO, 0, 0, 0);
            acc = __builtin_amdgcn_mfma_f32_32x32x16_bf16(Ahi, Blo[kt], acc, 0, 0, 0);
            acc = __builtin_amdgcn_mfma_f32_32x32x16_bf16(Alo, Bhi[kt], acc, 0, 0, 0);
        }

        if (g > 0) epi(pAcc, g - 1);       // deferred, hides in MFMA shadow
    }
    epi(acc, 15);                          // drain: tile 15

    // merge kg halves (lane L <-> L^32: same row, disjoint codes)
    const unsigned o1 = (unsigned)__shfl_xor((int)t1k, 32, 64);
    const unsigned o2 = (unsigned)__shfl_xor((int)t2k, 32, 64);
    const int     obt = __shfl_xor(btile, 32, 64);
    const unsigned m2k = umaxu(umaxu(t2k, o2), uminu(t1k, o1));
    const unsigned w1k = umaxu(t1k, o1);
    const int wkg = (o1 > t1k) ? (kg ^ 1) : kg;        // equal -> uncertain anyway
    const int wbt = (o1 > t1k) ? obt : btile;
    const float gap = __uint_as_float(w1k & 0xFFFFFFF0u) -
                      __uint_as_float(m2k & 0xFFFFFFF0u);
    const bool unc = gap < MARGIN;                     // ties: gap<=0 -> uncertain
    const int rr = 15 - (int)(w1k & 0xFu);
    const int code = wbt * 32 + (rr & 3) + 8 * (rr >> 2) + 4 * wkg;
    if (lane < 32 && !unc)
        out[(size_t)row * NCB + cbi] = code;

    unsigned long long msk = __ballot(unc && lane < 32);
    if (lane == 0 && msk) {
        const int n = __popcll(msk);
        int base = atomicAdd(unc_cnt, n);
        while (msk) {
            const int r = __ffsll(msk) - 1; msk &= msk - 1;
            unc_list[base++] = ((rowBase + wv * 32 + r) << 2) | cbi;
        }
    }
}

// ---------------------------------------------------------------------------
// Kernel 4 (v2): exact recheck, ONE BLOCK PER ITEM (grid-stride). Wave 0
// recomputes x exactly (f32 inp@proj); after barrier the 4 waves scan 128
// codes each; per-wave first-max reduce, LDS merge preferring lower wave
// (wave code-ranges disjoint ascending => first-max semantics). (r12, kept.)
// ---------------------------------------------------------------------------
__global__ __launch_bounds__(256) void recheck_kernel(
        const float* __restrict__ inp, const float* __restrict__ proj,
        const float* __restrict__ cbn,
        const int* __restrict__ unc_cnt, const int* __restrict__ unc_list,
        int* __restrict__ out) {
    __shared__ float sx[DEMB];
    __shared__ float sBest[4];
    __shared__ int   sIdx[4];
    const int lane = threadIdx.x & 63, wv = threadIdx.x >> 6;
    const int n = *unc_cnt;
    for (int it = blockIdx.x; it < n; it += gridDim.x) {
        const int item = unc_list[it];
        const int row = item >> 2, cbi = item & 3;
        if (wv == 0) {                     // exact x: lane owns cols lane,lane+64
            const float* ir = inp + (size_t)row * DIN;
            float a0 = 0.0f, a1 = 0.0f;
#pragma unroll 2
            for (int k = 0; k < DIN; k += 4) {
                const float4 iv = ld4(ir + k);
                const float* ivp = reinterpret_cast<const float*>(&iv);
#pragma unroll
                for (int j = 0; j < 4; ++j) {
                    a0 = fmaf(ivp[j], proj[(size_t)(k + j) * DEMB + lane],      a0);
                    a1 = fmaf(ivp[j], proj[(size_t)(k + j) * DEMB + lane + 64], a1);
                }
            }
            sx[lane] = a0; sx[lane + 64] = a1;
        }
        __syncthreads();

        float best = -INFINITY; int bi = 0;
#pragma unroll
        for (int j = 0; j < 2; ++j) {
            const int c = wv * 128 + lane + 64 * j;
            const float* cv = cbn + ((size_t)cbi * MCODES + c) * DEMB;
            float s0 = 0, s1 = 0, s2 = 0, s3 = 0;
#pragma unroll 4
            for (int k = 0; k < DEMB; k += 4) {
                const float4 xk = ld4(&sx[k]);
                const float4 ck = ld4(cv + k);
                s0 = fmaf(xk.x, ck.x, s0); s1 = fmaf(xk.y, ck.y, s1);
                s2 = fmaf(xk.z, ck.z, s2); s3 = fmaf(xk.w, ck.w, s3);
            }
            const float s = (s0 + s1) + (s2 + s3);
            if (s > best) { best = s; bi = c; }
        }
#pragma unroll
        for (int mm = 1; mm < 64; mm <<= 1) {
            const float ov = __shfl_xor(best, mm, 64);
            const int   oc = __shfl_xor(bi, mm, 64);
            if (ov > best || (ov == best && oc < bi)) { best = ov; bi = oc; }
        }
        if (lane == 0) { sBest[wv] = best; sIdx[wv] = bi; }
        __syncthreads();
        if (wv == 0 && lane == 0) {
            float b = sBest[0]; int bidx = sIdx[0];
#pragma unroll
            for (int w = 1; w < 4; ++w) {
                if (sBest[w] > b) { b = sBest[w]; bidx = sIdx[w]; }  // lower wave wins ties
            }
            out[(size_t)row * NCB + cbi] = bidx;
        }
        __syncthreads();                   // protect sx before next item
    }
}

// ---------------------------------------------------------------------------
// Fallback (ws too small): round-3 fused kernel (proven, 2 MB ws).
// ---------------------------------------------------------------------------
__global__ __launch_bounds__(256) void fused_quantize_kernel(
        const float* __restrict__ inp, const float* __restrict__ proj,
        const float* __restrict__ cbn, const unsigned short* __restrict__ cbA,
        int* __restrict__ out) {
    __shared__ float sX[128][132];
    __shared__ float sRn[128];
    const int tid = threadIdx.x;
    const int tx = tid & 31, ty = tid >> 5;
    const int rowBase = blockIdx.x * 128;

#pragma unroll 1
    for (int p = 0; p < 2; ++p) {
        float acc1[8][4];
#pragma unroll
        for (int i = 0; i < 8; ++i)
#pragma unroll
            for (int j = 0; j < 4; ++j) acc1[i][j] = 0.0f;
        const float* inRow0 = inp + (size_t)(rowBase + p * 64 + ty) * DIN;
        const float* pjCol  = proj + tx * 4;
        float4 ivA[8], ivB[8], pjA[4], pjB[4];
        auto load_step = [&](float4 iv[8], float4 pj[4], int kk) {
#pragma unroll
            for (int j = 0; j < 4; ++j) pj[j] = ld4(pjCol + (size_t)(kk + j) * DEMB);
#pragma unroll
            for (int i = 0; i < 8; ++i) iv[i] = ld4(inRow0 + (size_t)(8 * i) * DIN + kk);
        };
        auto fma_step = [&](const float4 iv[8], const float4 pj[4]) {
#pragma unroll
            for (int i = 0; i < 8; ++i) {
                const float* ivp = reinterpret_cast<const float*>(&iv[i]);
#pragma unroll
                for (int j = 0; j < 4; ++j) {
                    acc1[i][0] = fmaf(ivp[j], pj[j].x, acc1[i][0]);
                    acc1[i][1] = fmaf(ivp[j], pj[j].y, acc1[i][1]);
                    acc1[i][2] = fmaf(ivp[j], pj[j].z, acc1[i][2]);
                    acc1[i][3] = fmaf(ivp[j], pj[j].w, acc1[i][3]);
                }
            }
        };
        load_step(ivA, pjA, 0);
#pragma unroll 1
        for (int k = 0; k < DIN; k += 8) {
            load_step(ivB, pjB, k + 4);
            fma_step(ivA, pjA);
            if (k + 8 < DIN) load_step(ivA, pjA, k + 8);
            fma_step(ivB, pjB);
        }
#pragma unroll
        for (int i = 0; i < 8; ++i) {
            const int r = p * 64 + ty + 8 * i;
            float ss = acc1[i][0] * acc1[i][0] + acc1[i][1] * acc1[i][1] +
                       acc1[i][2] * acc1[i][2] + acc1[i][3] * acc1[i][3];
#pragma unroll
            for (int mm = 1; mm < 32; mm <<= 1) ss += __shfl_xor(ss, mm, 64);
            if (tx == 0) sRn[r] = 1.0f / sqrtf(ss);
            *reinterpret_cast<float4*>(&sX[r][tx * 4]) =
                make_float4(acc1[i][0], acc1[i][1], acc1[i][2], acc1[i][3]);
        }
    }
    __syncthreads();

    const int lane = tid & 63, wv = tid >> 6;
    const int kg = lane >> 5;
    const int rowL = wv * 32 + (lane & 31);
    bf16x8 Bhi[8], Blo[8];
    {
        const float rn = sRn[rowL];
#pragma unroll
        for (int kt = 0; kt < 8; ++kt) {
            const int k0 = kt * 16 + kg * 8;
            float4 f0 = ld4(&sX[rowL][k0]);
            float4 f1 = ld4(&sX[rowL][k0 + 4]);
            float xs[8] = {f0.x, f0.y, f0.z, f0.w, f1.x, f1.y, f1.z, f1.w};
            bf16x8 hv, lv;
#pragma unroll
            for (int e = 0; e < 8; ++e) {
                const float xn = xs[e] * rn;
                const unsigned short h = f2bf(xn);
                hv[e] = (short)h;
                lv[e] = (short)f2bf(xn - bf2f(h));
            }
            Bhi[kt] = hv; Blo[kt] = lv;
        }
    }
    float t1 = -INFINITY, t2 = -INFINITY; int i1 = 0;
    const short* pA = reinterpret_cast<const short*>(cbA) + (size_t)lane * 8;
#pragma unroll 1
    for (int ct = 0; ct < 64; ++ct) {
        if ((ct & 1) == 0) __syncthreads();
        const short* pct = pA + (size_t)ct * 8192;
        f32x16 accA, accB;
#pragma unroll
        for (int r = 0; r < 16; ++r) { accA[r] = 0.0f; accB[r] = 0.0f; }
#pragma unroll
        for (int kt = 0; kt < 8; ++kt) {
            const bf16x8 Ahi = *reinterpret_cast<const bf16x8*>(pct + kt * 1024);
            const bf16x8 Alo = *reinterpret_cast<const bf16x8*>(pct + kt * 1024 + 512);
            accA = __builtin_amdgcn_mfma_f32_32x32x16_bf16(Ahi, Bhi[kt], accA, 0, 0, 0);
            accB = __builtin_amdgcn_mfma_f32_32x32x16_bf16(Ahi, Blo[kt], accB, 0, 0, 0);
            accB = __builtin_amdgcn_mfma_f32_32x32x16_bf16(Alo, Bhi[kt], accB, 0, 0, 0);
        }
#pragma unroll
        for (int r = 0; r < 16; ++r) {
            const float v = accA[r] + accB[r];
            const int gidx = ct * 32 + ((r & 3) + 8 * (r >> 2) + 4 * kg);
            t2 = fmaxf(t2, fminf(v, t1));
            if (v > t1) { t1 = v; i1 = gidx; }
        }
        if ((ct & 15) == 15) {
            const int cbi = ct >> 4;
            const float o1 = __shfl_xor(t1, 32, 64);
            const float o2 = __shfl_xor(t2, 32, 64);
            const int   oi = __shfl_xor(i1, 32, 64);
            const float m2 = fmaxf(fmaxf(t2, o2), fminf(t1, o1));
            if (o1 > t1 || (o1 == t1 && oi < i1)) { t1 = o1; i1 = oi; }
            const bool unc = (t1 - m2) < MARGIN;
            if (lane < 32 && !unc)
                out[(size_t)(rowBase + rowL) * NCB + cbi] = i1 - cbi * MCODES;
            unsigned long long msk = __ballot(unc && lane < 32);
            while (msk) {
                const int r = __ffsll(msk) - 1; msk &= msk - 1;
                const int rl = wv * 32 + r;
                float best = -INFINITY; int bi = 0;
#pragma unroll 1
                for (int j = 0; j < 8; ++j) {
                    const int c = lane + 64 * j;
                    const float* cv = cbn + ((size_t)cbi * MCODES + c) * DEMB;
                    float s0 = 0, s1 = 0, s2 = 0, s3 = 0;
#pragma unroll
                    for (int k = 0; k < DEMB; k += 4) {
                        const float4 xk = ld4(&sX[rl][k]);
                        const float4 ck = ld4(cv + k);
                        s0 = fmaf(xk.x, ck.x, s0); s1 = fmaf(xk.y, ck.y, s1);
                        s2 = fmaf(xk.z, ck.z, s2); s3 = fmaf(xk.w, ck.w, s3);
                    }
                    const float s = (s0 + s1) + (s2 + s3);
                    if (s > best) { best = s; bi = c; }
                }
#pragma unroll
                for (int mm = 1; mm < 64; mm <<= 1) {
                    const float ov = __shfl_xor(best, mm, 64);
                    const int   oc = __shfl_xor(bi, mm, 64);
                    if (ov > best || (ov == best && oc < bi)) { best = ov; bi = oc; }
                }
                if (lane == 0) out[(size_t)(rowBase + rl) * NCB + cbi] = bi;
            }
            t1 = -INFINITY; t2 = -INFINITY; i1 = 0;
        }
    }
}

// ---------------------------------------------------------------------------
extern "C" void kernel_launch(void* const* d_in, const int* in_sizes, int n_in,
                              void* d_out, int out_size, void* d_ws, size_t ws_size,
                              hipStream_t stream) {
    const float* inp  = (const float*)d_in[0];   // [8,16,512,256]
    const float* proj = (const float*)d_in[1];   // [256,128]
    const float* cb   = (const float*)d_in[2];   // [4,512,128]
    int* out = (int*)d_out;                      // [8,16,512,4] int32

    char* ws = (char*)d_ws;
    float* cbn = (float*)ws;                                     // 1 MB
    unsigned short* cbA = (unsigned short*)(ws + (1 << 20));     // 1 MB
    float* xw  = (float*)(ws + (2 << 20) + (1 << 18));           // 32 MB
    const size_t off_cnt = (size_t)(2 << 20) + (1 << 18) + ((size_t)32 << 20);
    int* unc_cnt  = (int*)(ws + off_cnt);                        // 4 B (pad 256)
    int* unc_list = (int*)(ws + off_cnt + 256);                  // 1 MB
    const size_t off_pjA = off_cnt + 256 + (1 << 20);
    unsigned short* pjA = (unsigned short*)(ws + off_pjA);       // 192 KB
    const size_t need_old = off_pjA;
    const size_t need_new = off_pjA + 192 * 1024;

    hipLaunchKernelGGL(prep_codebook, dim3(NCODE / 4), dim3(256), 0, stream,
                       cb, cbn, cbA);
    if (ws_size >= need_old) {
        hipMemsetAsync(unc_cnt, 0, 4, stream);
        if (ws_size >= need_new) {
            hipLaunchKernelGGL(prep_proj, dim3(16), dim3(256), 0, stream, proj, pjA);
            hipLaunchKernelGGL(project_mfma, dim3(2048), dim3(256), 0, stream,
                               inp, pjA, xw);
        } else {
            hipLaunchKernelGGL(project_kernel, dim3(1024), dim3(256), 0, stream,
                               inp, proj, xw);
        }
        hipLaunchKernelGGL(sim_kernel, dim3(2048), dim3(256), 0, stream,
                           xw, cbA, out, unc_cnt, unc_list);
        hipLaunchKernelGGL(recheck_kernel, dim3(2048), dim3(256), 0, stream,
                           inp, proj, cbn, unc_cnt, unc_list, out);
    } else {
        hipLaunchKernelGGL(fused_quantize_kernel, dim3(512), dim3(256), 0, stream,
                           inp, proj, cbn, cbA, out);
    }
}